// Round 2
// baseline (640.612 us; speedup 1.0000x reference)
//
#include <hip/hip_runtime.h>

typedef unsigned short u16;
typedef __attribute__((ext_vector_type(8))) short bf16x8;
typedef __attribute__((ext_vector_type(4))) float f32x4;

__device__ __forceinline__ u16 f2bf(float f) {
  unsigned u = __float_as_uint(f);
  u += 0x7FFFu + ((u >> 16) & 1u);
  return (u16)(u >> 16);
}
__device__ __forceinline__ float bf2f(u16 h) {
  return __uint_as_float(((unsigned)h) << 16);
}

#define GLOAD16(g, l) __builtin_amdgcn_global_load_lds( \
    (const __attribute__((address_space(1))) void*)(g), \
    (__attribute__((address_space(3))) void*)(l), 16, 0, 0)

// ---------- elementwise converts ----------
__global__ __launch_bounds__(256) void cvtw_kernel(const float* __restrict__ in,
                                                   u16* __restrict__ out, int n4) {
  int i = blockIdx.x * 256 + threadIdx.x;
  if (i >= n4) return;
  float4 f = ((const float4*)in)[i];
  ushort4 u;
  u.x = f2bf(f.x); u.y = f2bf(f.y); u.z = f2bf(f.z); u.w = f2bf(f.w);
  ((ushort4*)out)[i] = u;
}

// gather x chunk: rows = ((s-s0)*128 + b)*4 + m , from hidden[s][m][b][0][h]
__global__ __launch_bounds__(256) void xcvt_kernel(const float* __restrict__ hidden,
                                                   u16* __restrict__ xb, int s0) {
  int idx = blockIdx.x * 256 + threadIdx.x;      // 0 .. 8192*256-1
  int h4 = idx & 255;
  int lrow = idx >> 8;                           // 0..8191
  int m = lrow & 3;
  int b = (lrow >> 2) & 127;
  int sl = lrow >> 9;                            // 0..15
  int s = s0 + sl;
  const float4 f = *(const float4*)(hidden + (((size_t)(s * 4 + m) * 128 + b) * 1024) + h4 * 4);
  ushort4 u;
  u.x = f2bf(f.x); u.y = f2bf(f.y); u.z = f2bf(f.z); u.w = f2bf(f.w);
  *(ushort4*)(xb + (size_t)lrow * 1024 + h4 * 4) = u;
}

// ---------- big GEMM: 256x256 tile, 8 waves, ring-3 LDS, counted vmcnt ----------
// C[m,n] = sum_k A[m,k]*Bw[n,k] + bias[n]; bf16 out.
// Requires M%256==0, N%256==0, K%32==0, K/32 >= 2.
__global__ __launch_bounds__(512, 2) void gemm256(const u16* __restrict__ A,
                                                  const u16* __restrict__ Bw,
                                                  const float* __restrict__ bias,
                                                  u16* __restrict__ C,
                                                  int N, int K) {
  __shared__ u16 SA[3][8192];   // 3 x 256rows x 32k (16KB each)
  __shared__ u16 SB[3][8192];
  const int t = threadIdx.x, w = t >> 6, l = t & 63;
  const int lr = l & 15, lg = l >> 4;
  const int wm = w >> 2, wn = w & 3;
  const int rowBase = blockIdx.y * 256, colBase = blockIdx.x * 256;

  // staging lane geometry: per gload instr, wave w writes rows [a*128+w*16, +16)
  // lane l -> row offset l>>2, phys 16B slot l&3; global slot = phys ^ (row&3)
  const int srow = l >> 2;
  const int gsl = ((l & 3) ^ (srow & 3)) * 8;   // element offset in row
  const u16* Ag0 = A + (size_t)(rowBase + w * 16 + srow) * K + gsl;
  const u16* Ag1 = Ag0 + (size_t)128 * K;
  const u16* Bg0 = Bw + (size_t)(colBase + w * 16 + srow) * K + gsl;
  const u16* Bg1 = Bg0 + (size_t)128 * K;

  // fragment read offsets (u16 units): LDS[row][slot^(row&3)] holds global slot
  const int fsl = (lg ^ (lr & 3)) * 8;
  const int aoffB = (wm * 128 + lr) * 32 + fsl;
  const int boffB = (wn * 64 + lr) * 32 + fsl;

  f32x4 acc[8][4];
#pragma unroll
  for (int i = 0; i < 8; i++)
#pragma unroll
    for (int j = 0; j < 4; j++) acc[i][j] = (f32x4){0.f, 0.f, 0.f, 0.f};

#define STG(tt, bb) do { \
    const int k0_ = (tt) * 32; \
    GLOAD16(Ag0 + k0_, &SA[bb][w * 512]); \
    GLOAD16(Ag1 + k0_, &SA[bb][4096 + w * 512]); \
    GLOAD16(Bg0 + k0_, &SB[bb][w * 512]); \
    GLOAD16(Bg1 + k0_, &SB[bb][4096 + w * 512]); \
  } while (0)

  const int nt = K >> 5;
  // prologue: stage tiles 0,1; publish tile 0
  STG(0, 0);
  STG(1, 1);
  asm volatile("s_waitcnt vmcnt(4)" ::: "memory");
  __builtin_amdgcn_s_barrier();
  asm volatile("" ::: "memory");

  int b0 = 0, b1 = 1, b2 = 2;
  for (int tile = 0; tile < nt; ++tile) {
    if (tile + 2 < nt) STG(tile + 2, b2);
    const u16* pa = SA[b0];
    const u16* pb = SB[b0];
    bf16x8 af[8], bfr[4];
#pragma unroll
    for (int i = 0; i < 8; i++) af[i] = *(const bf16x8*)(pa + aoffB + i * 512);
#pragma unroll
    for (int j = 0; j < 4; j++) bfr[j] = *(const bf16x8*)(pb + boffB + j * 512);
    __builtin_amdgcn_s_setprio(1);
#pragma unroll
    for (int i = 0; i < 8; i++)
#pragma unroll
      for (int j = 0; j < 4; j++)
        acc[i][j] = __builtin_amdgcn_mfma_f32_16x16x32_bf16(af[i], bfr[j], acc[i][j], 0, 0, 0);
    __builtin_amdgcn_s_setprio(0);
    // publish S(tile+1) for next iter; keep S(tile+2) (4 loads) in flight
    if (tile + 2 < nt) {
      asm volatile("s_waitcnt vmcnt(4)" ::: "memory");
    } else {
      asm volatile("s_waitcnt vmcnt(0)" ::: "memory");
    }
    __builtin_amdgcn_s_barrier();
    asm volatile("" ::: "memory");
    const int tmp = b0; b0 = b1; b1 = b2; b2 = tmp;
  }
#undef STG

  // epilogue: bias + bf16 store
  const int orow0 = rowBase + wm * 128 + lg * 4;
  const int ocol0 = colBase + wn * 64 + lr;
#pragma unroll
  for (int i = 0; i < 8; i++) {
#pragma unroll
    for (int j = 0; j < 4; j++) {
      const int col = ocol0 + j * 16;
      const float bv = bias[col];
#pragma unroll
      for (int r = 0; r < 4; r++) {
        const int row = orow0 + i * 16 + r;
        C[(size_t)row * N + col] = f2bf(acc[i][j][r] + bv);
      }
    }
  }
}

// ---------- small GEMM (m97 structure, 128x128 tile) for N=1024 epilogue modes ----------
// MODE 1: bf16 out, row t -> s=t>>7,b=t&127, u=b*64+s; += pos_enc[s][col]
// MODE 2: f32 out, row u -> s=u&63,b=u>>6; out[(s*128+b)*1024+col]
template <int MODE>
__global__ __launch_bounds__(256) void gemm_bt(const u16* __restrict__ A,
                                               const u16* __restrict__ Bw,
                                               const float* __restrict__ bias,
                                               void* __restrict__ Cout,
                                               int M, int N, int K,
                                               const float* __restrict__ posenc) {
  __shared__ u16 As[128 * 32];
  __shared__ u16 Bs[128 * 32];
  const int t = threadIdx.x;
  const int w = t >> 6, l = t & 63;
  const int rowBase = blockIdx.y * 128, colBase = blockIdx.x * 128;
  const int wr = (w >> 1) * 64, wc = (w & 1) * 64;
  const int lr = l & 15, lg = l >> 4;
  const int sl = (lg ^ (lr & 3)) * 8;

  const int r0 = t >> 2,         s0 = (((t) & 3) ^ (r0 & 3)) * 8;
  const int r1 = (t + 256) >> 2, s1 = (((t + 256) & 3) ^ (r1 & 3)) * 8;
  const u16* A0 = A + (size_t)(rowBase + r0) * K + s0;
  const u16* A1 = A + (size_t)(rowBase + r1) * K + s1;
  const u16* B0 = Bw + (size_t)(colBase + r0) * K + s0;
  const u16* B1 = Bw + (size_t)(colBase + r1) * K + s1;
  u16* lA0 = As + (w * 64) * 8;
  u16* lA1 = As + (256 + w * 64) * 8;
  u16* lB0 = Bs + (w * 64) * 8;
  u16* lB1 = Bs + (256 + w * 64) * 8;

  f32x4 acc[4][4];
#pragma unroll
  for (int i = 0; i < 4; i++)
#pragma unroll
    for (int j = 0; j < 4; j++) acc[i][j] = (f32x4){0.f, 0.f, 0.f, 0.f};

  for (int k0 = 0; k0 < K; k0 += 32) {
    GLOAD16(A0 + k0, lA0);
    GLOAD16(A1 + k0, lA1);
    GLOAD16(B0 + k0, lB0);
    GLOAD16(B1 + k0, lB1);
    __syncthreads();
    bf16x8 af[4], bfv[4];
#pragma unroll
    for (int i = 0; i < 4; i++) af[i] = *(const bf16x8*)(As + (wr + i * 16 + lr) * 32 + sl);
#pragma unroll
    for (int j = 0; j < 4; j++) bfv[j] = *(const bf16x8*)(Bs + (wc + j * 16 + lr) * 32 + sl);
#pragma unroll
    for (int i = 0; i < 4; i++)
#pragma unroll
      for (int j = 0; j < 4; j++)
        acc[i][j] = __builtin_amdgcn_mfma_f32_16x16x32_bf16(af[i], bfv[j], acc[i][j], 0, 0, 0);
    __syncthreads();
  }

  const int orow0 = rowBase + wr + lg * 4;
  const int ocol0 = colBase + wc + lr;
#pragma unroll
  for (int i = 0; i < 4; i++) {
#pragma unroll
    for (int j = 0; j < 4; j++) {
#pragma unroll
      for (int r = 0; r < 4; r++) {
        int row = orow0 + i * 16 + r;
        int col = ocol0 + j * 16;
        float v = acc[i][j][r] + bias[col];
        if (MODE == 1) {
          int s = row >> 7, b = row & 127;
          v += posenc[s * 1024 + col];
          ((u16*)Cout)[((size_t)(b * 64 + s)) * 1024 + col] = f2bf(v);
        } else {
          int s = row & 63, b = row >> 6;
          ((float*)Cout)[((size_t)(s * 128 + b)) * 1024 + col] = v;
        }
      }
    }
  }
}

// ---------- attention A: L=4, per (seq,head) one wave; outputs mean over the 4 queries ----------
__global__ __launch_bounds__(256) void attn1_kernel(const u16* __restrict__ qkv,
                                                    u16* __restrict__ am, int seqBase) {
  const int w = threadIdx.x >> 6, l = threadIdx.x & 63;
  const int pair = blockIdx.x * 4 + w;   // 0..16383
  const int seq = pair >> 3, head = pair & 7;
  const int d0 = l * 2;
  const u16* base = qkv + (size_t)(seq * 4) * 3072 + head * 128 + d0;
  const float scale = 0.08838834764831845f;  // 1/sqrt(128)
  float q[4][2], k[4][2], v[4][2];
#pragma unroll
  for (int m = 0; m < 4; m++) {
    ushort2 uq = *(const ushort2*)(base + (size_t)m * 3072);
    ushort2 uk = *(const ushort2*)(base + (size_t)m * 3072 + 1024);
    ushort2 uv = *(const ushort2*)(base + (size_t)m * 3072 + 2048);
    q[m][0] = bf2f(uq.x) * scale; q[m][1] = bf2f(uq.y) * scale;
    k[m][0] = bf2f(uk.x);         k[m][1] = bf2f(uk.y);
    v[m][0] = bf2f(uv.x);         v[m][1] = bf2f(uv.y);
  }
  float sc[4][4];
#pragma unroll
  for (int i = 0; i < 4; i++)
#pragma unroll
    for (int j = 0; j < 4; j++)
      sc[i][j] = q[i][0] * k[j][0] + q[i][1] * k[j][1];
#pragma unroll
  for (int off = 32; off >= 1; off >>= 1)
#pragma unroll
    for (int i = 0; i < 4; i++)
#pragma unroll
      for (int j = 0; j < 4; j++)
        sc[i][j] += __shfl_xor(sc[i][j], off, 64);
  float pbar[4] = {0.f, 0.f, 0.f, 0.f};
#pragma unroll
  for (int i = 0; i < 4; i++) {
    float mx = fmaxf(fmaxf(sc[i][0], sc[i][1]), fmaxf(sc[i][2], sc[i][3]));
    float e0 = __expf(sc[i][0] - mx), e1 = __expf(sc[i][1] - mx);
    float e2 = __expf(sc[i][2] - mx), e3 = __expf(sc[i][3] - mx);
    float inv = 0.25f / (e0 + e1 + e2 + e3);
    pbar[0] += e0 * inv; pbar[1] += e1 * inv; pbar[2] += e2 * inv; pbar[3] += e3 * inv;
  }
  float o0 = pbar[0] * v[0][0] + pbar[1] * v[1][0] + pbar[2] * v[2][0] + pbar[3] * v[3][0];
  float o1 = pbar[0] * v[0][1] + pbar[1] * v[1][1] + pbar[2] * v[2][1] + pbar[3] * v[3][1];
  ushort2 ou; ou.x = f2bf(o0); ou.y = f2bf(o1);
  *(ushort2*)(am + (size_t)(seqBase + seq) * 1024 + head * 128 + d0) = ou;
}

// ---------- attention B: L=64, one block per (b,head); full-tile MFMA attention ----------
__global__ __launch_bounds__(256) void attn2_kernel(const u16* __restrict__ qkv2,
                                                    u16* __restrict__ aout) {
  __shared__ u16 Qs[64 * 128];   // slot-swizzled (16B slots, slot ^= row&7)
  __shared__ u16 Ks[64 * 128];
  __shared__ u16 Vt[128 * 72];   // transposed V, padded rows
  __shared__ u16 Ps[64 * 72];    // probabilities, padded
  const int t = threadIdx.x, w = t >> 6, l = t & 63;
  const int lr = l & 15, lg = l >> 4;
  const int b = blockIdx.x >> 3, head = blockIdx.x & 7;
  const u16* qb = qkv2 + (size_t)(b * 64) * 3072 + head * 128;

#pragma unroll
  for (int c = 0; c < 4; c++) {
    int flat = c * 256 + t;
    int row = flat >> 4, sp = flat & 15;
    int sg = (sp ^ (row & 7)) * 8;
    GLOAD16(qb + (size_t)row * 3072 + sg, Qs + (c * 256 + w * 64) * 8);
    GLOAD16(qb + 1024 + (size_t)row * 3072 + sg, Ks + (c * 256 + w * 64) * 8);
  }
  const int dd = (t & 63) * 2, kb = t >> 6;
#pragma unroll
  for (int c = 0; c < 16; c++) {
    int k = c * 4 + kb;
    ushort2 vv = *(const ushort2*)(qb + 2048 + (size_t)k * 3072 + dd);
    Vt[(size_t)dd * 72 + k] = vv.x;
    Vt[(size_t)(dd + 1) * 72 + k] = vv.y;
  }
  __syncthreads();

  f32x4 sc[4];
#pragma unroll
  for (int cb = 0; cb < 4; cb++) sc[cb] = (f32x4){0.f, 0.f, 0.f, 0.f};
#pragma unroll
  for (int ks = 0; ks < 4; ks++) {
    bf16x8 aq = *(const bf16x8*)(Qs + (w * 16 + lr) * 128 + ((ks * 4 + lg) ^ (lr & 7)) * 8);
#pragma unroll
    for (int cb = 0; cb < 4; cb++) {
      bf16x8 bk = *(const bf16x8*)(Ks + (cb * 16 + lr) * 128 + ((ks * 4 + lg) ^ (lr & 7)) * 8);
      sc[cb] = __builtin_amdgcn_mfma_f32_16x16x32_bf16(aq, bk, sc[cb], 0, 0, 0);
    }
  }

  const float scale = 0.08838834764831845f;
#pragma unroll
  for (int r = 0; r < 4; r++) {
#pragma unroll
    for (int cb = 0; cb < 4; cb++) sc[cb][r] *= scale;
    float mx = fmaxf(fmaxf(sc[0][r], sc[1][r]), fmaxf(sc[2][r], sc[3][r]));
#pragma unroll
    for (int off = 1; off < 16; off <<= 1) mx = fmaxf(mx, __shfl_xor(mx, off, 64));
    float sum = 0.f;
#pragma unroll
    for (int cb = 0; cb < 4; cb++) {
      float e = __expf(sc[cb][r] - mx);
      sum += e;
      sc[cb][r] = e;
    }
#pragma unroll
    for (int off = 1; off < 16; off <<= 1) sum += __shfl_xor(sum, off, 64);
    float inv = 1.f / sum;
    int prow = w * 16 + lg * 4 + r;
#pragma unroll
    for (int cb = 0; cb < 4; cb++)
      Ps[(size_t)prow * 72 + cb * 16 + lr] = f2bf(sc[cb][r] * inv);
  }

  f32x4 o[8];
#pragma unroll
  for (int cb = 0; cb < 8; cb++) o[cb] = (f32x4){0.f, 0.f, 0.f, 0.f};
#pragma unroll
  for (int ks = 0; ks < 2; ks++) {
    bf16x8 ap = *(const bf16x8*)(Ps + (w * 16 + lr) * 72 + ks * 32 + lg * 8);
#pragma unroll
    for (int cb = 0; cb < 8; cb++) {
      bf16x8 bv = *(const bf16x8*)(Vt + (cb * 16 + lr) * 72 + ks * 32 + lg * 8);
      o[cb] = __builtin_amdgcn_mfma_f32_16x16x32_bf16(ap, bv, o[cb], 0, 0, 0);
    }
  }
#pragma unroll
  for (int cb = 0; cb < 8; cb++) {
#pragma unroll
    for (int r = 0; r < 4; r++) {
      int srow = w * 16 + lg * 4 + r;
      int d = cb * 16 + lr;
      aout[(size_t)(b * 64 + srow) * 1024 + head * 128 + d] = f2bf(o[cb][r]);
    }
  }
}

extern "C" void kernel_launch(void* const* d_in, const int* in_sizes, int n_in,
                              void* d_out, int out_size, void* d_ws, size_t ws_size,
                              hipStream_t stream) {
  const float* hidden   = (const float*)d_in[0];
  const float* mf_in_w  = (const float*)d_in[1];
  const float* mf_in_b  = (const float*)d_in[2];
  const float* mf_out_w = (const float*)d_in[3];
  const float* mf_out_b = (const float*)d_in[4];
  const float* sf_in_w  = (const float*)d_in[5];
  const float* sf_in_b  = (const float*)d_in[6];
  const float* sf_out_w = (const float*)d_in[7];
  const float* sf_out_b = (const float*)d_in[8];
  const float* pos_enc  = (const float*)d_in[9];

  char* ws = (char*)d_ws;
  u16* w_mf_in  = (u16*)(ws);              // 6291456
  u16* w_mf_out = (u16*)(ws + 6291456);    // 2097152
  u16* w_sf_in  = (u16*)(ws + 8388608);    // 6291456
  u16* w_sf_out = (u16*)(ws + 14680064);   // 2097152
  u16* xchunk   = (u16*)(ws + 16777216);   // 16777216
  u16* qkvbuf   = (u16*)(ws + 33554432);   // 50331648
  u16* attnmean = (u16*)(ws + 83886080);   // 16777216
  u16* seqbuf   = (u16*)(ws + 100663296);  // 16777216
  u16* a2out    = (u16*)(ws + 117440512);  // 16777216 -> total 134217728 (128 MB)

  cvtw_kernel<<<3072, 256, 0, stream>>>(mf_in_w, w_mf_in, 786432);
  cvtw_kernel<<<1024, 256, 0, stream>>>(mf_out_w, w_mf_out, 262144);
  cvtw_kernel<<<3072, 256, 0, stream>>>(sf_in_w, w_sf_in, 786432);
  cvtw_kernel<<<1024, 256, 0, stream>>>(sf_out_w, w_sf_out, 262144);

  for (int c = 0; c < 4; ++c) {
    xcvt_kernel<<<8192, 256, 0, stream>>>(hidden, xchunk, c * 16);
    gemm256<<<dim3(12, 32), 512, 0, stream>>>(xchunk, w_mf_in, mf_in_b, qkvbuf,
                                              3072, 1024);
    attn1_kernel<<<4096, 256, 0, stream>>>(qkvbuf, attnmean, c * 2048);
  }

  gemm_bt<1><<<dim3(8, 64), 256, 0, stream>>>(attnmean, w_mf_out, mf_out_b, seqbuf,
                                              8192, 1024, 1024, pos_enc);
  gemm256<<<dim3(12, 32), 512, 0, stream>>>(seqbuf, w_sf_in, sf_in_b, qkvbuf,
                                            3072, 1024);
  attn2_kernel<<<1024, 256, 0, stream>>>(qkvbuf, a2out);
  gemm_bt<2><<<dim3(8, 64), 256, 0, stream>>>(a2out, w_sf_out, sf_out_b, d_out,
                                              8192, 1024, 1024, nullptr);
}

// Round 3
// 530.163 us; speedup vs baseline: 1.2083x; 1.2083x over previous
//
#include <hip/hip_runtime.h>

typedef unsigned short u16;
typedef __attribute__((ext_vector_type(8))) short bf16x8;
typedef __attribute__((ext_vector_type(4))) float f32x4;

__device__ __forceinline__ u16 f2bf(float f) {
  unsigned u = __float_as_uint(f);
  u += 0x7FFFu + ((u >> 16) & 1u);
  return (u16)(u >> 16);
}
__device__ __forceinline__ float bf2f(u16 h) {
  return __uint_as_float(((unsigned)h) << 16);
}

#define GLOAD16(g, l) __builtin_amdgcn_global_load_lds( \
    (const __attribute__((address_space(1))) void*)(g), \
    (__attribute__((address_space(3))) void*)(l), 16, 0, 0)

// ---------- elementwise converts ----------
__global__ __launch_bounds__(256) void cvtw_kernel(const float* __restrict__ in,
                                                   u16* __restrict__ out, int n4) {
  int i = blockIdx.x * 256 + threadIdx.x;
  if (i >= n4) return;
  float4 f = ((const float4*)in)[i];
  ushort4 u;
  u.x = f2bf(f.x); u.y = f2bf(f.y); u.z = f2bf(f.z); u.w = f2bf(f.w);
  ((ushort4*)out)[i] = u;
}

// gather x chunk: rows = ((s-s0)*128 + b)*4 + m , from hidden[s][m][b][0][h]
__global__ __launch_bounds__(256) void xcvt_kernel(const float* __restrict__ hidden,
                                                   u16* __restrict__ xb, int s0) {
  int idx = blockIdx.x * 256 + threadIdx.x;      // 0 .. 8192*256-1
  int h4 = idx & 255;
  int lrow = idx >> 8;                           // 0..8191
  int m = lrow & 3;
  int b = (lrow >> 2) & 127;
  int sl = lrow >> 9;                            // 0..15
  int s = s0 + sl;
  const float4 f = *(const float4*)(hidden + (((size_t)(s * 4 + m) * 128 + b) * 1024) + h4 * 4);
  ushort4 u;
  u.x = f2bf(f.x); u.y = f2bf(f.y); u.z = f2bf(f.z); u.w = f2bf(f.w);
  *(ushort4*)(xb + (size_t)lrow * 1024 + h4 * 4) = u;
}

// ---------- fine-pipelined GEMM: BM=256 BN=128 BK=32, 4 waves, ring-3 LDS ----------
// C[m,n] = sum_k A[m,k]*Bw[n,k] + bias[n]
// MODE 0: bf16 out, C[row*N+col]
// MODE 1: bf16 out, row -> s=row>>7,b=row&127; += posenc[s][col]; out[(b*64+s)*1024+col]
// MODE 2: f32 out, row -> s=row&63,b=row>>6; out[(s*128+b)*1024+col]
// Requires M%256==0, N%128==0, K%32==0, K/32>=3, grid blocks %8==0.
template <int MODE>
__global__ __launch_bounds__(256, 2) void gemm_fp(const u16* __restrict__ A,
                                                  const u16* __restrict__ Bw,
                                                  const float* __restrict__ bias,
                                                  void* __restrict__ Cout,
                                                  int N, int K,
                                                  const float* __restrict__ posenc) {
  __shared__ u16 SA[3][8192];   // 3 x (256 rows x 32 k) = 48 KB
  __shared__ u16 SB[3][4096];   // 3 x (128 rows x 32 k) = 24 KB
  const int t = threadIdx.x, w = t >> 6, l = t & 63;
  const int lr = l & 15, lg = l >> 4;
  const int wm = w >> 1, wn = w & 1;   // wave tile 128x64

  // XCD-aware bijective swizzle (grid blocks % 8 == 0)
  const int gx = gridDim.x;
  const int nb = gx * gridDim.y;
  const int id = blockIdx.y * gx + blockIdx.x;
  const int id2 = (id & 7) * (nb >> 3) + (id >> 3);
  const int rowBase = (id2 / gx) * 256, colBase = (id2 % gx) * 128;

  // staging geometry: per call, wave w covers rows [base + w*16, +16); lane l ->
  // row +(l>>2), 16B slot (l&3); global slot = (l&3) ^ (row&3)
  const int srow = l >> 2;
  const int ssl = ((l & 3) ^ (srow & 3)) * 8;
  const u16* Ag = A + (size_t)(rowBase + w * 16 + srow) * K + ssl;
  const u16* Bg = Bw + (size_t)(colBase + w * 16 + srow) * K + ssl;
  u16* const lA = &SA[0][0] + w * 512;   // + buf*8192 + call*2048
  u16* const lB = &SB[0][0] + w * 512;   // + buf*4096 + call*2048

  // fragment read offsets: row*32 + (lg ^ (row&3))*8 ; row&3 == lr&3
  const int fsw = (lg ^ (lr & 3)) * 8;
  const int aoff = (wm * 128 + lr) * 32 + fsw;
  const int boff = (wn * 64 + lr) * 32 + fsw;

  f32x4 acc[8][4];
#pragma unroll
  for (int i = 0; i < 8; i++)
#pragma unroll
    for (int j = 0; j < 4; j++) acc[i][j] = (f32x4){0.f, 0.f, 0.f, 0.f};

#define STG_P0(tt, bb) do { \
    const size_t ko_ = (size_t)(tt) * 32; \
    GLOAD16(Ag + ko_,                    lA + (bb) * 8192); \
    GLOAD16(Ag + ko_ + (size_t)64 * K,   lA + (bb) * 8192 + 2048); \
    GLOAD16(Ag + ko_ + (size_t)128 * K,  lA + (bb) * 8192 + 4096); \
  } while (0)
#define STG_P1(tt, bb) do { \
    const size_t ko_ = (size_t)(tt) * 32; \
    GLOAD16(Ag + ko_ + (size_t)192 * K,  lA + (bb) * 8192 + 6144); \
    GLOAD16(Bg + ko_,                    lB + (bb) * 4096); \
    GLOAD16(Bg + ko_ + (size_t)64 * K,   lB + (bb) * 4096 + 2048); \
  } while (0)

  const int nt = K >> 5;
  // prologue: stage tiles 0,1
  STG_P0(0, 0); STG_P1(0, 0);
  STG_P0(1, 1); STG_P1(1, 1);
  asm volatile("s_waitcnt vmcnt(6)" ::: "memory");   // tile 0 landed
  __builtin_amdgcn_s_barrier();

  int bcur = 0;
  for (int tt = 0; tt < nt; ++tt) {
    const u16* pa = &SA[bcur][0];
    const u16* pb = &SB[bcur][0];
    const int bnext = (bcur + 2 > 2) ? bcur - 1 : bcur + 2;  // (bcur+2)%3
    bf16x8 af[4], bfr[4];

    // ---- phase 0: m-frags 0-3 x all n ----
#pragma unroll
    for (int m = 0; m < 4; m++) af[m] = *(const bf16x8*)(pa + aoff + m * 512);
#pragma unroll
    for (int n = 0; n < 4; n++) bfr[n] = *(const bf16x8*)(pb + boff + n * 512);
    if (tt + 2 < nt) STG_P0(tt + 2, bnext);
    __builtin_amdgcn_s_barrier();
    asm volatile("s_waitcnt lgkmcnt(0)" ::: "memory");
    __builtin_amdgcn_sched_barrier(0);
    __builtin_amdgcn_s_setprio(1);
#pragma unroll
    for (int m = 0; m < 4; m++)
#pragma unroll
      for (int n = 0; n < 4; n++)
        acc[m][n] = __builtin_amdgcn_mfma_f32_16x16x32_bf16(af[m], bfr[n], acc[m][n], 0, 0, 0);
    __builtin_amdgcn_s_setprio(0);
    __builtin_amdgcn_s_barrier();

    // ---- phase 1: m-frags 4-7 x all n (B reused in regs) ----
#pragma unroll
    for (int m = 0; m < 4; m++) af[m] = *(const bf16x8*)(pa + aoff + (m + 4) * 512);
    if (tt + 2 < nt) STG_P1(tt + 2, bnext);
    __builtin_amdgcn_s_barrier();
    asm volatile("s_waitcnt lgkmcnt(0)" ::: "memory");
    __builtin_amdgcn_sched_barrier(0);
    __builtin_amdgcn_s_setprio(1);
#pragma unroll
    for (int m = 0; m < 4; m++)
#pragma unroll
      for (int n = 0; n < 4; n++)
        acc[m + 4][n] = __builtin_amdgcn_mfma_f32_16x16x32_bf16(af[m], bfr[n], acc[m + 4][n], 0, 0, 0);
    __builtin_amdgcn_s_setprio(0);
    if (tt + 2 < nt) {
      asm volatile("s_waitcnt vmcnt(6)" ::: "memory");   // tile tt+1 landed; tt+2 in flight
    } else if (tt + 1 < nt) {
      asm volatile("s_waitcnt vmcnt(0)" ::: "memory");   // drain for final tile
    }
    __builtin_amdgcn_s_barrier();
    bcur = (bcur + 1 > 2) ? 0 : bcur + 1;
  }
#undef STG_P0
#undef STG_P1

  // epilogue
  const int orow0 = rowBase + wm * 128 + lg * 4;
  const int ocol0 = colBase + wn * 64 + lr;
#pragma unroll
  for (int m = 0; m < 8; m++) {
#pragma unroll
    for (int n = 0; n < 4; n++) {
      const int col = ocol0 + n * 16;
      const float bv = bias[col];
#pragma unroll
      for (int r = 0; r < 4; r++) {
        const int row = orow0 + m * 16 + r;
        float v = acc[m][n][r] + bv;
        if (MODE == 0) {
          ((u16*)Cout)[(size_t)row * N + col] = f2bf(v);
        } else if (MODE == 1) {
          int s = row >> 7, b = row & 127;
          v += posenc[s * 1024 + col];
          ((u16*)Cout)[((size_t)(b * 64 + s)) * 1024 + col] = f2bf(v);
        } else {
          int s = row & 63, b = row >> 6;
          ((float*)Cout)[((size_t)(s * 128 + b)) * 1024 + col] = v;
        }
      }
    }
  }
}

// ---------- attention A: L=4, per (seq,head) one wave; outputs mean over the 4 queries ----------
__global__ __launch_bounds__(256) void attn1_kernel(const u16* __restrict__ qkv,
                                                    u16* __restrict__ am, int seqBase) {
  const int w = threadIdx.x >> 6, l = threadIdx.x & 63;
  const int pair = blockIdx.x * 4 + w;   // 0..16383
  const int seq = pair >> 3, head = pair & 7;
  const int d0 = l * 2;
  const u16* base = qkv + (size_t)(seq * 4) * 3072 + head * 128 + d0;
  const float scale = 0.08838834764831845f;  // 1/sqrt(128)
  float q[4][2], k[4][2], v[4][2];
#pragma unroll
  for (int m = 0; m < 4; m++) {
    ushort2 uq = *(const ushort2*)(base + (size_t)m * 3072);
    ushort2 uk = *(const ushort2*)(base + (size_t)m * 3072 + 1024);
    ushort2 uv = *(const ushort2*)(base + (size_t)m * 3072 + 2048);
    q[m][0] = bf2f(uq.x) * scale; q[m][1] = bf2f(uq.y) * scale;
    k[m][0] = bf2f(uk.x);         k[m][1] = bf2f(uk.y);
    v[m][0] = bf2f(uv.x);         v[m][1] = bf2f(uv.y);
  }
  float sc[4][4];
#pragma unroll
  for (int i = 0; i < 4; i++)
#pragma unroll
    for (int j = 0; j < 4; j++)
      sc[i][j] = q[i][0] * k[j][0] + q[i][1] * k[j][1];
#pragma unroll
  for (int off = 32; off >= 1; off >>= 1)
#pragma unroll
    for (int i = 0; i < 4; i++)
#pragma unroll
      for (int j = 0; j < 4; j++)
        sc[i][j] += __shfl_xor(sc[i][j], off, 64);
  float pbar[4] = {0.f, 0.f, 0.f, 0.f};
#pragma unroll
  for (int i = 0; i < 4; i++) {
    float mx = fmaxf(fmaxf(sc[i][0], sc[i][1]), fmaxf(sc[i][2], sc[i][3]));
    float e0 = __expf(sc[i][0] - mx), e1 = __expf(sc[i][1] - mx);
    float e2 = __expf(sc[i][2] - mx), e3 = __expf(sc[i][3] - mx);
    float inv = 0.25f / (e0 + e1 + e2 + e3);
    pbar[0] += e0 * inv; pbar[1] += e1 * inv; pbar[2] += e2 * inv; pbar[3] += e3 * inv;
  }
  float o0 = pbar[0] * v[0][0] + pbar[1] * v[1][0] + pbar[2] * v[2][0] + pbar[3] * v[3][0];
  float o1 = pbar[0] * v[0][1] + pbar[1] * v[1][1] + pbar[2] * v[2][1] + pbar[3] * v[3][1];
  ushort2 ou; ou.x = f2bf(o0); ou.y = f2bf(o1);
  *(ushort2*)(am + (size_t)(seqBase + seq) * 1024 + head * 128 + d0) = ou;
}

// ---------- attention B: L=64, one block per (b,head); full-tile MFMA attention ----------
__global__ __launch_bounds__(256) void attn2_kernel(const u16* __restrict__ qkv2,
                                                    u16* __restrict__ aout) {
  __shared__ u16 Qs[64 * 128];   // slot-swizzled (16B slots, slot ^= row&7)
  __shared__ u16 Ks[64 * 128];
  __shared__ u16 Vt[128 * 72];   // transposed V, padded rows
  __shared__ u16 Ps[64 * 72];    // probabilities, padded
  const int t = threadIdx.x, w = t >> 6, l = t & 63;
  const int lr = l & 15, lg = l >> 4;
  const int b = blockIdx.x >> 3, head = blockIdx.x & 7;
  const u16* qb = qkv2 + (size_t)(b * 64) * 3072 + head * 128;

#pragma unroll
  for (int c = 0; c < 4; c++) {
    int flat = c * 256 + t;
    int row = flat >> 4, sp = flat & 15;
    int sg = (sp ^ (row & 7)) * 8;
    GLOAD16(qb + (size_t)row * 3072 + sg, Qs + (c * 256 + w * 64) * 8);
    GLOAD16(qb + 1024 + (size_t)row * 3072 + sg, Ks + (c * 256 + w * 64) * 8);
  }
  const int dd = (t & 63) * 2, kb = t >> 6;
#pragma unroll
  for (int c = 0; c < 16; c++) {
    int k = c * 4 + kb;
    ushort2 vv = *(const ushort2*)(qb + 2048 + (size_t)k * 3072 + dd);
    Vt[(size_t)dd * 72 + k] = vv.x;
    Vt[(size_t)(dd + 1) * 72 + k] = vv.y;
  }
  __syncthreads();

  f32x4 sc[4];
#pragma unroll
  for (int cb = 0; cb < 4; cb++) sc[cb] = (f32x4){0.f, 0.f, 0.f, 0.f};
#pragma unroll
  for (int ks = 0; ks < 4; ks++) {
    bf16x8 aq = *(const bf16x8*)(Qs + (w * 16 + lr) * 128 + ((ks * 4 + lg) ^ (lr & 7)) * 8);
#pragma unroll
    for (int cb = 0; cb < 4; cb++) {
      bf16x8 bk = *(const bf16x8*)(Ks + (cb * 16 + lr) * 128 + ((ks * 4 + lg) ^ (lr & 7)) * 8);
      sc[cb] = __builtin_amdgcn_mfma_f32_16x16x32_bf16(aq, bk, sc[cb], 0, 0, 0);
    }
  }

  const float scale = 0.08838834764831845f;
#pragma unroll
  for (int r = 0; r < 4; r++) {
#pragma unroll
    for (int cb = 0; cb < 4; cb++) sc[cb][r] *= scale;
    float mx = fmaxf(fmaxf(sc[0][r], sc[1][r]), fmaxf(sc[2][r], sc[3][r]));
#pragma unroll
    for (int off = 1; off < 16; off <<= 1) mx = fmaxf(mx, __shfl_xor(mx, off, 64));
    float sum = 0.f;
#pragma unroll
    for (int cb = 0; cb < 4; cb++) {
      float e = __expf(sc[cb][r] - mx);
      sum += e;
      sc[cb][r] = e;
    }
#pragma unroll
    for (int off = 1; off < 16; off <<= 1) sum += __shfl_xor(sum, off, 64);
    float inv = 1.f / sum;
    int prow = w * 16 + lg * 4 + r;
#pragma unroll
    for (int cb = 0; cb < 4; cb++)
      Ps[(size_t)prow * 72 + cb * 16 + lr] = f2bf(sc[cb][r] * inv);
  }

  f32x4 o[8];
#pragma unroll
  for (int cb = 0; cb < 8; cb++) o[cb] = (f32x4){0.f, 0.f, 0.f, 0.f};
#pragma unroll
  for (int ks = 0; ks < 2; ks++) {
    bf16x8 ap = *(const bf16x8*)(Ps + (w * 16 + lr) * 72 + ks * 32 + lg * 8);
#pragma unroll
    for (int cb = 0; cb < 8; cb++) {
      bf16x8 bv = *(const bf16x8*)(Vt + (cb * 16 + lr) * 72 + ks * 32 + lg * 8);
      o[cb] = __builtin_amdgcn_mfma_f32_16x16x32_bf16(ap, bv, o[cb], 0, 0, 0);
    }
  }
#pragma unroll
  for (int cb = 0; cb < 8; cb++) {
#pragma unroll
    for (int r = 0; r < 4; r++) {
      int srow = w * 16 + lg * 4 + r;
      int d = cb * 16 + lr;
      aout[(size_t)(b * 64 + srow) * 1024 + head * 128 + d] = f2bf(o[cb][r]);
    }
  }
}

extern "C" void kernel_launch(void* const* d_in, const int* in_sizes, int n_in,
                              void* d_out, int out_size, void* d_ws, size_t ws_size,
                              hipStream_t stream) {
  const float* hidden   = (const float*)d_in[0];
  const float* mf_in_w  = (const float*)d_in[1];
  const float* mf_in_b  = (const float*)d_in[2];
  const float* mf_out_w = (const float*)d_in[3];
  const float* mf_out_b = (const float*)d_in[4];
  const float* sf_in_w  = (const float*)d_in[5];
  const float* sf_in_b  = (const float*)d_in[6];
  const float* sf_out_w = (const float*)d_in[7];
  const float* sf_out_b = (const float*)d_in[8];
  const float* pos_enc  = (const float*)d_in[9];

  char* ws = (char*)d_ws;
  u16* w_mf_in  = (u16*)(ws);              // 6291456
  u16* w_mf_out = (u16*)(ws + 6291456);    // 2097152
  u16* w_sf_in  = (u16*)(ws + 8388608);    // 6291456
  u16* w_sf_out = (u16*)(ws + 14680064);   // 2097152
  u16* xchunk   = (u16*)(ws + 16777216);   // 16777216
  u16* qkvbuf   = (u16*)(ws + 33554432);   // 50331648
  u16* attnmean = (u16*)(ws + 83886080);   // 16777216
  u16* seqbuf   = (u16*)(ws + 100663296);  // 16777216
  u16* a2out    = (u16*)(ws + 117440512);  // 16777216 -> total 134217728 (128 MB)

  cvtw_kernel<<<3072, 256, 0, stream>>>(mf_in_w, w_mf_in, 786432);
  cvtw_kernel<<<1024, 256, 0, stream>>>(mf_out_w, w_mf_out, 262144);
  cvtw_kernel<<<3072, 256, 0, stream>>>(sf_in_w, w_sf_in, 786432);
  cvtw_kernel<<<1024, 256, 0, stream>>>(sf_out_w, w_sf_out, 262144);

  for (int c = 0; c < 4; ++c) {
    xcvt_kernel<<<8192, 256, 0, stream>>>(hidden, xchunk, c * 16);
    gemm_fp<0><<<dim3(24, 32), 256, 0, stream>>>(xchunk, w_mf_in, mf_in_b, qkvbuf,
                                                 3072, 1024, nullptr);
    attn1_kernel<<<4096, 256, 0, stream>>>(qkvbuf, attnmean, c * 2048);
  }

  gemm_fp<1><<<dim3(8, 32), 256, 0, stream>>>(attnmean, w_mf_out, mf_out_b, seqbuf,
                                              1024, 1024, pos_enc);
  gemm_fp<0><<<dim3(24, 32), 256, 0, stream>>>(seqbuf, w_sf_in, sf_in_b, qkvbuf,
                                               3072, 1024, nullptr);
  attn2_kernel<<<1024, 256, 0, stream>>>(qkvbuf, a2out);
  gemm_fp<2><<<dim3(8, 32), 256, 0, stream>>>(a2out, w_sf_out, sf_out_b, d_out,
                                              1024, 1024, nullptr);
}

// Round 5
// 478.588 us; speedup vs baseline: 1.3385x; 1.1078x over previous
//
#include <hip/hip_runtime.h>

typedef unsigned short u16;
typedef __attribute__((ext_vector_type(8))) short bf16x8;
typedef __attribute__((ext_vector_type(4))) float f32x4;

__device__ __forceinline__ u16 f2bf(float f) {
  unsigned u = __float_as_uint(f);
  u += 0x7FFFu + ((u >> 16) & 1u);
  return (u16)(u >> 16);
}
__device__ __forceinline__ float bf2f(u16 h) {
  return __uint_as_float(((unsigned)h) << 16);
}

#define GLOAD16(g, l) __builtin_amdgcn_global_load_lds( \
    (const __attribute__((address_space(1))) void*)(g), \
    (__attribute__((address_space(3))) void*)(l), 16, 0, 0)

// ---------- elementwise converts ----------
__global__ __launch_bounds__(256) void cvtw_kernel(const float* __restrict__ in,
                                                   u16* __restrict__ out, int n4) {
  int i = blockIdx.x * 256 + threadIdx.x;
  if (i >= n4) return;
  float4 f = ((const float4*)in)[i];
  ushort4 u;
  u.x = f2bf(f.x); u.y = f2bf(f.y); u.z = f2bf(f.z); u.w = f2bf(f.w);
  ((ushort4*)out)[i] = u;
}

// gather x rows = ((s-s0)*128 + b)*4 + m from hidden[s][m][b][0][h]
__global__ __launch_bounds__(256) void xcvt_kernel(const float* __restrict__ hidden,
                                                   u16* __restrict__ xb, int s0) {
  int idx = blockIdx.x * 256 + threadIdx.x;
  int h4 = idx & 255;
  int lrow = idx >> 8;
  int m = lrow & 3;
  int b = (lrow >> 2) & 127;
  int sl = lrow >> 9;
  int s = s0 + sl;
  const float4 f = *(const float4*)(hidden + (((size_t)(s * 4 + m) * 128 + b) * 1024) + h4 * 4);
  ushort4 u;
  u.x = f2bf(f.x); u.y = f2bf(f.y); u.z = f2bf(f.z); u.w = f2bf(f.w);
  *(ushort4*)(xb + (size_t)lrow * 1024 + h4 * 4) = u;
}

// ---------- 8-phase 256x256 GEMM, BK=64, 8 waves, counted vmcnt ----------
// C[m,n] = sum_k A[m,k]*Bw[n,k] + bias[n], bf16 out. KK = K (compile-time).
// LDS slabs: A(d,kh) at ((d*2+kh)*8192), B at +32768; slab = 256 rows x 32 k,
// row stride 32 elems, 4x16B slots/row, slot' = slot ^ ((row>>1)&3).
template <int KK>
__global__ __launch_bounds__(512, 2) void gemm8p(const u16* __restrict__ A,
                                                 const u16* __restrict__ Bw,
                                                 const float* __restrict__ bias,
                                                 u16* __restrict__ C, int N) {
  __shared__ u16 Sh[65536];   // 128 KB
  const int t = threadIdx.x, w = t >> 6, l = t & 63;
  const int lr = l & 15, lg = l >> 4;
  const int wm = w >> 2, wn = w & 3;

  // XCD-aware bijective swizzle (grid blocks % 8 == 0)
  const int gx = gridDim.x;
  const int nb = gx * gridDim.y;
  const int id = blockIdx.y * gx + blockIdx.x;
  const int id2 = (id & 7) * (nb >> 3) + (id >> 3);
  const int rowBase = (id2 / gx) * 256, colBase = (id2 % gx) * 256;

  // staging: instr covers 128 slab-rows; lane t -> row (t>>2), slot' (t&3),
  // source slot = (t&3) ^ ((t>>3)&3)  [since swz(row)=(row>>1)&3]
  const int sslot8 = ((t & 3) ^ ((t >> 3) & 3)) * 8;
  const u16* Ag = A + (size_t)(rowBase + (t >> 2)) * KK + sslot8;
  const u16* Bg = Bw + (size_t)(colBase + (t >> 2)) * KK + sslot8;
  const size_t K128 = (size_t)128 * KK;
  const int ldsW = w * 512;   // wave-uniform stage dest (elems)

  // frag reads: row = (wgroup + frag*16 + lr), slot' = lg ^ ((lr>>1)&3)
  const int fslot8 = (lg ^ ((lr >> 1) & 3)) * 8;
  const int aRowOff = (wm * 128 + lr) * 32 + fslot8;
  const int bRowOff = (wn * 64 + lr) * 32 + fslot8;

  f32x4 acc[8][4];
#pragma unroll
  for (int i = 0; i < 8; i++)
#pragma unroll
    for (int j = 0; j < 4; j++) acc[i][j] = (f32x4){0.f, 0.f, 0.f, 0.f};
  bf16x8 af[4], bfr[4];

#define STGA(tt, KH, DB) { \
    const u16* g_ = Ag + (size_t)(tt) * 64 + (KH) * 32; \
    GLOAD16(g_, Sh + ((DB) * 2 + (KH)) * 8192 + ldsW); \
    GLOAD16(g_ + K128, Sh + ((DB) * 2 + (KH)) * 8192 + 4096 + ldsW); }
#define STGB(tt, KH, DB) { \
    const u16* g_ = Bg + (size_t)(tt) * 64 + (KH) * 32; \
    GLOAD16(g_, Sh + 32768 + ((DB) * 2 + (KH)) * 8192 + ldsW); \
    GLOAD16(g_ + K128, Sh + 32768 + ((DB) * 2 + (KH)) * 8192 + 4096 + ldsW); }

#define PHASE(DD, KH, MG, DOB, STG, WT) do { \
    const u16* sa_ = Sh + ((DD) * 2 + (KH)) * 8192 + aRowOff; \
    _Pragma("unroll") \
    for (int mi = 0; mi < 4; mi++) af[mi] = *(const bf16x8*)(sa_ + ((MG) * 4 + mi) * 512); \
    if (DOB) { \
      const u16* sb_ = Sh + 32768 + ((DD) * 2 + (KH)) * 8192 + bRowOff; \
      _Pragma("unroll") \
      for (int n = 0; n < 4; n++) bfr[n] = *(const bf16x8*)(sb_ + n * 512); \
    } \
    STG; \
    __builtin_amdgcn_s_barrier(); \
    asm volatile("s_waitcnt lgkmcnt(0)" ::: "memory"); \
    __builtin_amdgcn_sched_barrier(0); \
    __builtin_amdgcn_s_setprio(1); \
    _Pragma("unroll") \
    for (int mi = 0; mi < 4; mi++) { \
      _Pragma("unroll") \
      for (int n = 0; n < 4; n++) \
        acc[(MG) * 4 + mi][n] = \
            __builtin_amdgcn_mfma_f32_16x16x32_bf16(af[mi], bfr[n], acc[(MG) * 4 + mi][n], 0, 0, 0); \
    } \
    __builtin_amdgcn_s_setprio(0); \
    WT; \
    __builtin_amdgcn_s_barrier(); \
  } while (0)

  // prologue: K-tile 0 (all), K-tile 1 kh0; vmcnt(4) leaves K-tile-1-kh0 in flight
  STGA(0, 0, 0); STGB(0, 0, 0);
  STGA(0, 1, 0); STGB(0, 1, 0);
  STGA(1, 0, 1); STGB(1, 0, 1);
  asm volatile("s_waitcnt vmcnt(4)" ::: "memory");
  __builtin_amdgcn_s_barrier();

  const int NIT = KK / 128;   // 2 K-tiles per iteration
  int t0 = 0;
  for (int it = 0; it < NIT - 1; ++it, t0 += 2) {
    PHASE(0, 0, 0, 1, STGA(t0 + 1, 1, 1), );
    PHASE(0, 0, 1, 0, STGB(t0 + 1, 1, 1), );
    PHASE(0, 1, 0, 1, STGA(t0 + 2, 0, 0), );
    PHASE(0, 1, 1, 0, STGB(t0 + 2, 0, 0), asm volatile("s_waitcnt vmcnt(4)" ::: "memory"));
    PHASE(1, 0, 0, 1, STGA(t0 + 2, 1, 0), );
    PHASE(1, 0, 1, 0, STGB(t0 + 2, 1, 0), );
    PHASE(1, 1, 0, 1, STGA(t0 + 3, 0, 1), );
    PHASE(1, 1, 1, 0, STGB(t0 + 3, 0, 1), asm volatile("s_waitcnt vmcnt(4)" ::: "memory"));
  }
  // peeled last iteration: stage only K-tile (t0+1).kh1, drain at ph3
  PHASE(0, 0, 0, 1, STGA(t0 + 1, 1, 1), );
  PHASE(0, 0, 1, 0, STGB(t0 + 1, 1, 1), );
  PHASE(0, 1, 0, 1, , );
  PHASE(0, 1, 1, 0, , asm volatile("s_waitcnt vmcnt(0)" ::: "memory"));
  PHASE(1, 0, 0, 1, , );
  PHASE(1, 0, 1, 0, , );
  PHASE(1, 1, 0, 1, , );
  PHASE(1, 1, 1, 0, , );
#undef PHASE
#undef STGA
#undef STGB

  // epilogue: bias + bf16 store
  const int orow0 = rowBase + wm * 128 + lg * 4;
  const int ocol0 = colBase + wn * 64 + lr;
#pragma unroll
  for (int m = 0; m < 8; m++) {
#pragma unroll
    for (int n = 0; n < 4; n++) {
      const int col = ocol0 + n * 16;
      const float bv = bias[col];
#pragma unroll
      for (int r = 0; r < 4; r++) {
        const int row = orow0 + m * 16 + r;
        C[(size_t)row * N + col] = f2bf(acc[m][n][r] + bv);
      }
    }
  }
}

// ---------- small GEMM (fine-pipelined, BM=256 BN=128 BK=32, ring-3) ----------
// MODE 1: bf16 out, row -> s=row>>7,b=row&127; += posenc[s][col]; out[(b*64+s)*1024+col]
// MODE 2: f32 out, row -> s=row&63,b=row>>6; out[(s*128+b)*1024+col]
template <int MODE>
__global__ __launch_bounds__(256, 2) void gemm_fp(const u16* __restrict__ A,
                                                  const u16* __restrict__ Bw,
                                                  const float* __restrict__ bias,
                                                  void* __restrict__ Cout,
                                                  int N, int K,
                                                  const float* __restrict__ posenc) {
  __shared__ u16 SA[3][8192];
  __shared__ u16 SB[3][4096];
  const int t = threadIdx.x, w = t >> 6, l = t & 63;
  const int lr = l & 15, lg = l >> 4;
  const int wm = w >> 1, wn = w & 1;

  const int gx = gridDim.x;
  const int nb = gx * gridDim.y;
  const int id = blockIdx.y * gx + blockIdx.x;
  const int id2 = (id & 7) * (nb >> 3) + (id >> 3);
  const int rowBase = (id2 / gx) * 256, colBase = (id2 % gx) * 128;

  const int srow = l >> 2;
  const int ssl = ((l & 3) ^ (srow & 3)) * 8;
  const u16* Ag = A + (size_t)(rowBase + w * 16 + srow) * K + ssl;
  const u16* Bg = Bw + (size_t)(colBase + w * 16 + srow) * K + ssl;
  u16* const lA = &SA[0][0] + w * 512;
  u16* const lB = &SB[0][0] + w * 512;

  const int fsw = (lg ^ (lr & 3)) * 8;
  const int aoff = (wm * 128 + lr) * 32 + fsw;
  const int boff = (wn * 64 + lr) * 32 + fsw;

  f32x4 acc[8][4];
#pragma unroll
  for (int i = 0; i < 8; i++)
#pragma unroll
    for (int j = 0; j < 4; j++) acc[i][j] = (f32x4){0.f, 0.f, 0.f, 0.f};

#define STG_P0(tt, bb) do { \
    const size_t ko_ = (size_t)(tt) * 32; \
    GLOAD16(Ag + ko_,                    lA + (bb) * 8192); \
    GLOAD16(Ag + ko_ + (size_t)64 * K,   lA + (bb) * 8192 + 2048); \
    GLOAD16(Ag + ko_ + (size_t)128 * K,  lA + (bb) * 8192 + 4096); \
  } while (0)
#define STG_P1(tt, bb) do { \
    const size_t ko_ = (size_t)(tt) * 32; \
    GLOAD16(Ag + ko_ + (size_t)192 * K,  lA + (bb) * 8192 + 6144); \
    GLOAD16(Bg + ko_,                    lB + (bb) * 4096); \
    GLOAD16(Bg + ko_ + (size_t)64 * K,   lB + (bb) * 4096 + 2048); \
  } while (0)

  const int nt = K >> 5;
  STG_P0(0, 0); STG_P1(0, 0);
  STG_P0(1, 1); STG_P1(1, 1);
  asm volatile("s_waitcnt vmcnt(6)" ::: "memory");
  __builtin_amdgcn_s_barrier();

  int bcur = 0;
  for (int tt = 0; tt < nt; ++tt) {
    const u16* pa = &SA[bcur][0];
    const u16* pb = &SB[bcur][0];
    const int bnext = (bcur + 2 > 2) ? bcur - 1 : bcur + 2;
    bf16x8 af[4], bfr[4];

#pragma unroll
    for (int m = 0; m < 4; m++) af[m] = *(const bf16x8*)(pa + aoff + m * 512);
#pragma unroll
    for (int n = 0; n < 4; n++) bfr[n] = *(const bf16x8*)(pb + boff + n * 512);
    if (tt + 2 < nt) STG_P0(tt + 2, bnext);
    __builtin_amdgcn_s_barrier();
    asm volatile("s_waitcnt lgkmcnt(0)" ::: "memory");
    __builtin_amdgcn_sched_barrier(0);
    __builtin_amdgcn_s_setprio(1);
#pragma unroll
    for (int m = 0; m < 4; m++)
#pragma unroll
      for (int n = 0; n < 4; n++)
        acc[m][n] = __builtin_amdgcn_mfma_f32_16x16x32_bf16(af[m], bfr[n], acc[m][n], 0, 0, 0);
    __builtin_amdgcn_s_setprio(0);
    __builtin_amdgcn_s_barrier();

#pragma unroll
    for (int m = 0; m < 4; m++) af[m] = *(const bf16x8*)(pa + aoff + (m + 4) * 512);
    if (tt + 2 < nt) STG_P1(tt + 2, bnext);
    __builtin_amdgcn_s_barrier();
    asm volatile("s_waitcnt lgkmcnt(0)" ::: "memory");
    __builtin_amdgcn_sched_barrier(0);
    __builtin_amdgcn_s_setprio(1);
#pragma unroll
    for (int m = 0; m < 4; m++)
#pragma unroll
      for (int n = 0; n < 4; n++)
        acc[m + 4][n] = __builtin_amdgcn_mfma_f32_16x16x32_bf16(af[m], bfr[n], acc[m + 4][n], 0, 0, 0);
    __builtin_amdgcn_s_setprio(0);
    if (tt + 2 < nt) {
      asm volatile("s_waitcnt vmcnt(6)" ::: "memory");
    } else if (tt + 1 < nt) {
      asm volatile("s_waitcnt vmcnt(0)" ::: "memory");
    }
    __builtin_amdgcn_s_barrier();
    bcur = (bcur + 1 > 2) ? 0 : bcur + 1;
  }
#undef STG_P0
#undef STG_P1

  const int orow0 = rowBase + wm * 128 + lg * 4;
  const int ocol0 = colBase + wn * 64 + lr;
#pragma unroll
  for (int m = 0; m < 8; m++) {
#pragma unroll
    for (int n = 0; n < 4; n++) {
      const int col = ocol0 + n * 16;
      const float bv = bias[col];
#pragma unroll
      for (int r = 0; r < 4; r++) {
        const int row = orow0 + m * 16 + r;
        float v = acc[m][n][r] + bv;
        if (MODE == 1) {
          int s = row >> 7, b = row & 127;
          v += posenc[s * 1024 + col];
          ((u16*)Cout)[((size_t)(b * 64 + s)) * 1024 + col] = f2bf(v);
        } else {
          int s = row & 63, b = row >> 6;
          ((float*)Cout)[((size_t)(s * 128 + b)) * 1024 + col] = v;
        }
      }
    }
  }
}

// ---------- attention A ----------
__global__ __launch_bounds__(256) void attn1_kernel(const u16* __restrict__ qkv,
                                                    u16* __restrict__ am, int seqBase) {
  const int w = threadIdx.x >> 6, l = threadIdx.x & 63;
  const int pair = blockIdx.x * 4 + w;
  const int seq = pair >> 3, head = pair & 7;
  const int d0 = l * 2;
  const u16* base = qkv + (size_t)(seq * 4) * 3072 + head * 128 + d0;
  const float scale = 0.08838834764831845f;
  float q[4][2], k[4][2], v[4][2];
#pragma unroll
  for (int m = 0; m < 4; m++) {
    ushort2 uq = *(const ushort2*)(base + (size_t)m * 3072);
    ushort2 uk = *(const ushort2*)(base + (size_t)m * 3072 + 1024);
    ushort2 uv = *(const ushort2*)(base + (size_t)m * 3072 + 2048);
    q[m][0] = bf2f(uq.x) * scale; q[m][1] = bf2f(uq.y) * scale;
    k[m][0] = bf2f(uk.x);         k[m][1] = bf2f(uk.y);
    v[m][0] = bf2f(uv.x);         v[m][1] = bf2f(uv.y);
  }
  float sc[4][4];
#pragma unroll
  for (int i = 0; i < 4; i++)
#pragma unroll
    for (int j = 0; j < 4; j++)
      sc[i][j] = q[i][0] * k[j][0] + q[i][1] * k[j][1];
#pragma unroll
  for (int off = 32; off >= 1; off >>= 1)
#pragma unroll
    for (int i = 0; i < 4; i++)
#pragma unroll
      for (int j = 0; j < 4; j++)
        sc[i][j] += __shfl_xor(sc[i][j], off, 64);
  float pbar[4] = {0.f, 0.f, 0.f, 0.f};
#pragma unroll
  for (int i = 0; i < 4; i++) {
    float mx = fmaxf(fmaxf(sc[i][0], sc[i][1]), fmaxf(sc[i][2], sc[i][3]));
    float e0 = __expf(sc[i][0] - mx), e1 = __expf(sc[i][1] - mx);
    float e2 = __expf(sc[i][2] - mx), e3 = __expf(sc[i][3] - mx);
    float inv = 0.25f / (e0 + e1 + e2 + e3);
    pbar[0] += e0 * inv; pbar[1] += e1 * inv; pbar[2] += e2 * inv; pbar[3] += e3 * inv;
  }
  float o0 = pbar[0] * v[0][0] + pbar[1] * v[1][0] + pbar[2] * v[2][0] + pbar[3] * v[3][0];
  float o1 = pbar[0] * v[0][1] + pbar[1] * v[1][1] + pbar[2] * v[2][1] + pbar[3] * v[3][1];
  ushort2 ou; ou.x = f2bf(o0); ou.y = f2bf(o1);
  *(ushort2*)(am + (size_t)(seqBase + seq) * 1024 + head * 128 + d0) = ou;
}

// ---------- attention B ----------
__global__ __launch_bounds__(256) void attn2_kernel(const u16* __restrict__ qkv2,
                                                    u16* __restrict__ aout) {
  __shared__ u16 Qs[64 * 128];
  __shared__ u16 Ks[64 * 128];
  __shared__ u16 Vt[128 * 72];
  __shared__ u16 Ps[64 * 72];
  const int t = threadIdx.x, w = t >> 6, l = t & 63;
  const int lr = l & 15, lg = l >> 4;
  const int b = blockIdx.x >> 3, head = blockIdx.x & 7;
  const u16* qb = qkv2 + (size_t)(b * 64) * 3072 + head * 128;

#pragma unroll
  for (int c = 0; c < 4; c++) {
    int flat = c * 256 + t;
    int row = flat >> 4, sp = flat & 15;
    int sg = (sp ^ (row & 7)) * 8;
    GLOAD16(qb + (size_t)row * 3072 + sg, Qs + (c * 256 + w * 64) * 8);
    GLOAD16(qb + 1024 + (size_t)row * 3072 + sg, Ks + (c * 256 + w * 64) * 8);
  }
  const int dd = (t & 63) * 2, kb = t >> 6;
#pragma unroll
  for (int c = 0; c < 16; c++) {
    int k = c * 4 + kb;
    ushort2 vv = *(const ushort2*)(qb + 2048 + (size_t)k * 3072 + dd);
    Vt[(size_t)dd * 72 + k] = vv.x;
    Vt[(size_t)(dd + 1) * 72 + k] = vv.y;
  }
  __syncthreads();

  f32x4 sc[4];
#pragma unroll
  for (int cb = 0; cb < 4; cb++) sc[cb] = (f32x4){0.f, 0.f, 0.f, 0.f};
#pragma unroll
  for (int ks = 0; ks < 4; ks++) {
    bf16x8 aq = *(const bf16x8*)(Qs + (w * 16 + lr) * 128 + ((ks * 4 + lg) ^ (lr & 7)) * 8);
#pragma unroll
    for (int cb = 0; cb < 4; cb++) {
      bf16x8 bk = *(const bf16x8*)(Ks + (cb * 16 + lr) * 128 + ((ks * 4 + lg) ^ (lr & 7)) * 8);
      sc[cb] = __builtin_amdgcn_mfma_f32_16x16x32_bf16(aq, bk, sc[cb], 0, 0, 0);
    }
  }

  const float scale = 0.08838834764831845f;
#pragma unroll
  for (int r = 0; r < 4; r++) {
#pragma unroll
    for (int cb = 0; cb < 4; cb++) sc[cb][r] *= scale;
    float mx = fmaxf(fmaxf(sc[0][r], sc[1][r]), fmaxf(sc[2][r], sc[3][r]));
#pragma unroll
    for (int off = 1; off < 16; off <<= 1) mx = fmaxf(mx, __shfl_xor(mx, off, 64));
    float sum = 0.f;
#pragma unroll
    for (int cb = 0; cb < 4; cb++) {
      float e = __expf(sc[cb][r] - mx);
      sum += e;
      sc[cb][r] = e;
    }
#pragma unroll
    for (int off = 1; off < 16; off <<= 1) sum += __shfl_xor(sum, off, 64);
    float inv = 1.f / sum;
    int prow = w * 16 + lg * 4 + r;
#pragma unroll
    for (int cb = 0; cb < 4; cb++)
      Ps[(size_t)prow * 72 + cb * 16 + lr] = f2bf(sc[cb][r] * inv);
  }

  f32x4 o[8];
#pragma unroll
  for (int cb = 0; cb < 8; cb++) o[cb] = (f32x4){0.f, 0.f, 0.f, 0.f};
#pragma unroll
  for (int ks = 0; ks < 2; ks++) {
    bf16x8 ap = *(const bf16x8*)(Ps + (w * 16 + lr) * 72 + ks * 32 + lg * 8);
#pragma unroll
    for (int cb = 0; cb < 8; cb++) {
      bf16x8 bv = *(const bf16x8*)(Vt + (cb * 16 + lr) * 72 + ks * 32 + lg * 8);
      o[cb] = __builtin_amdgcn_mfma_f32_16x16x32_bf16(ap, bv, o[cb], 0, 0, 0);
    }
  }
#pragma unroll
  for (int cb = 0; cb < 8; cb++) {
#pragma unroll
    for (int r = 0; r < 4; r++) {
      int srow = w * 16 + lg * 4 + r;
      int d = cb * 16 + lr;
      aout[(size_t)(b * 64 + srow) * 1024 + head * 128 + d] = f2bf(o[cb][r]);
    }
  }
}

extern "C" void kernel_launch(void* const* d_in, const int* in_sizes, int n_in,
                              void* d_out, int out_size, void* d_ws, size_t ws_size,
                              hipStream_t stream) {
  const float* hidden   = (const float*)d_in[0];
  const float* mf_in_w  = (const float*)d_in[1];
  const float* mf_in_b  = (const float*)d_in[2];
  const float* mf_out_w = (const float*)d_in[3];
  const float* mf_out_b = (const float*)d_in[4];
  const float* sf_in_w  = (const float*)d_in[5];
  const float* sf_in_b  = (const float*)d_in[6];
  const float* sf_out_w = (const float*)d_in[7];
  const float* sf_out_b = (const float*)d_in[8];
  const float* pos_enc  = (const float*)d_in[9];

  char* ws = (char*)d_ws;
  u16* w_mf_in  = (u16*)(ws);              // 6291456
  u16* w_mf_out = (u16*)(ws + 6291456);    // 2097152
  u16* w_sf_in  = (u16*)(ws + 8388608);    // 6291456
  u16* w_sf_out = (u16*)(ws + 14680064);   // 2097152

  cvtw_kernel<<<3072, 256, 0, stream>>>(mf_in_w, w_mf_in, 786432);
  cvtw_kernel<<<1024, 256, 0, stream>>>(mf_out_w, w_mf_out, 262144);
  cvtw_kernel<<<3072, 256, 0, stream>>>(sf_in_w, w_sf_in, 786432);
  cvtw_kernel<<<1024, 256, 0, stream>>>(sf_out_w, w_sf_out, 262144);

  if (ws_size >= 335544320ull) {
    // full-M path: one GEMM1 dispatch over all 32768 rows
    u16* xfull    = (u16*)(ws + 16777216);   // 64 MB
    u16* qkvfull  = (u16*)(ws + 83886080);   // 192 MB
    u16* attnmean = (u16*)(ws + 285212672);  // 16 MB
    u16* seqbuf   = (u16*)(ws + 301989888);  // 16 MB
    u16* a2out    = (u16*)(ws + 318767104);  // 16 MB -> 320 MB total

    xcvt_kernel<<<32768, 256, 0, stream>>>(hidden, xfull, 0);
    gemm8p<1024><<<dim3(12, 128), 512, 0, stream>>>(xfull, w_mf_in, mf_in_b, qkvfull, 3072);
    // 8192 seqs x 8 heads / 4 waves = 16384 blocks (NOT 65536 — R4's OOB bug)
    attn1_kernel<<<16384, 256, 0, stream>>>(qkvfull, attnmean, 0);

    gemm_fp<1><<<dim3(8, 32), 256, 0, stream>>>(attnmean, w_mf_out, mf_out_b, seqbuf,
                                                1024, 1024, pos_enc);
    gemm8p<1024><<<dim3(12, 32), 512, 0, stream>>>(seqbuf, w_sf_in, sf_in_b, qkvfull, 3072);
    attn2_kernel<<<1024, 256, 0, stream>>>(qkvfull, a2out);
    gemm_fp<2><<<dim3(8, 32), 256, 0, stream>>>(a2out, w_sf_out, sf_out_b, d_out,
                                                1024, 1024, nullptr);
  } else {
    // chunked fallback (128 MB)
    u16* xchunk   = (u16*)(ws + 16777216);
    u16* qkvbuf   = (u16*)(ws + 33554432);
    u16* attnmean = (u16*)(ws + 83886080);
    u16* seqbuf   = (u16*)(ws + 100663296);
    u16* a2out    = (u16*)(ws + 117440512);

    for (int c = 0; c < 4; ++c) {
      xcvt_kernel<<<8192, 256, 0, stream>>>(hidden, xchunk, c * 16);
      gemm8p<1024><<<dim3(12, 32), 512, 0, stream>>>(xchunk, w_mf_in, mf_in_b, qkvbuf, 3072);
      attn1_kernel<<<4096, 256, 0, stream>>>(qkvbuf, attnmean, c * 2048);
    }

    gemm_fp<1><<<dim3(8, 32), 256, 0, stream>>>(attnmean, w_mf_out, mf_out_b, seqbuf,
                                                1024, 1024, pos_enc);
    gemm8p<1024><<<dim3(12, 32), 512, 0, stream>>>(seqbuf, w_sf_in, sf_in_b, qkvbuf, 3072);
    attn2_kernel<<<1024, 256, 0, stream>>>(qkvbuf, a2out);
    gemm_fp<2><<<dim3(8, 32), 256, 0, stream>>>(a2out, w_sf_out, sf_out_b, d_out,
                                                1024, 1024, nullptr);
  }
}

// Round 6
// 475.415 us; speedup vs baseline: 1.3475x; 1.0067x over previous
//
#include <hip/hip_runtime.h>

typedef unsigned short u16;
typedef __attribute__((ext_vector_type(8))) short bf16x8;
typedef __attribute__((ext_vector_type(4))) float f32x4;

__device__ __forceinline__ u16 f2bf(float f) {
  unsigned u = __float_as_uint(f);
  u += 0x7FFFu + ((u >> 16) & 1u);
  return (u16)(u >> 16);
}
__device__ __forceinline__ float bf2f(u16 h) {
  return __uint_as_float(((unsigned)h) << 16);
}

#define GLOAD16(g, l) __builtin_amdgcn_global_load_lds( \
    (const __attribute__((address_space(1))) void*)(g), \
    (__attribute__((address_space(3))) void*)(l), 16, 0, 0)

// ---------- elementwise converts ----------
__global__ __launch_bounds__(256) void cvtw_kernel(const float* __restrict__ in,
                                                   u16* __restrict__ out, int n4) {
  int i = blockIdx.x * 256 + threadIdx.x;
  if (i >= n4) return;
  float4 f = ((const float4*)in)[i];
  ushort4 u;
  u.x = f2bf(f.x); u.y = f2bf(f.y); u.z = f2bf(f.z); u.w = f2bf(f.w);
  ((ushort4*)out)[i] = u;
}

// gather x rows = ((s-s0)*128 + b)*4 + m from hidden[s][m][b][0][h]
__global__ __launch_bounds__(256) void xcvt_kernel(const float* __restrict__ hidden,
                                                   u16* __restrict__ xb, int s0) {
  int idx = blockIdx.x * 256 + threadIdx.x;
  int h4 = idx & 255;
  int lrow = idx >> 8;
  int m = lrow & 3;
  int b = (lrow >> 2) & 127;
  int sl = lrow >> 9;
  int s = s0 + sl;
  const float4 f = *(const float4*)(hidden + (((size_t)(s * 4 + m) * 128 + b) * 1024) + h4 * 4);
  ushort4 u;
  u.x = f2bf(f.x); u.y = f2bf(f.y); u.z = f2bf(f.z); u.w = f2bf(f.w);
  *(ushort4*)(xb + (size_t)lrow * 1024 + h4 * 4) = u;
}

// ---------- 8-phase 256x256 GEMM, BK=64, 8 waves, deep counted vmcnt ----------
// C[m,n] = sum_k A[m,k]*Bw[n,k] + bias[n], bf16 out. KK = K (compile-time).
// LDS slabs: A(d,kh) at ((d*2+kh)*8192), B at +32768; slab = 256 rows x 32 k,
// row stride 32 elems, 4x16B slots/row, slot' = slot ^ ((row>>1)&3).
// Ledger (steady): 8 loads in flight; vmcnt(8) at ph1/3/5/7 forces exactly the
// 4 loads issued 5-6 phases earlier — the slab read two phases later.
template <int KK>
__global__ __launch_bounds__(512, 2) void gemm8p(const u16* __restrict__ A,
                                                 const u16* __restrict__ Bw,
                                                 const float* __restrict__ bias,
                                                 u16* __restrict__ C, int N) {
  __shared__ u16 Sh[65536];   // 128 KB
  const int t = threadIdx.x, w = t >> 6, l = t & 63;
  const int lr = l & 15, lg = l >> 4;
  const int wm = w >> 2, wn = w & 3;

  // XCD-aware bijective swizzle (grid blocks % 8 == 0)
  const int gx = gridDim.x;
  const int nb = gx * gridDim.y;
  const int id = blockIdx.y * gx + blockIdx.x;
  const int id2 = (id & 7) * (nb >> 3) + (id >> 3);
  const int rowBase = (id2 / gx) * 256, colBase = (id2 % gx) * 256;

  // staging: instr covers 128 slab-rows; lane t -> row (t>>2), slot' (t&3),
  // source slot = (t&3) ^ ((t>>3)&3)  [since swz(row)=(row>>1)&3]
  const int sslot8 = ((t & 3) ^ ((t >> 3) & 3)) * 8;
  const u16* Ag = A + (size_t)(rowBase + (t >> 2)) * KK + sslot8;
  const u16* Bg = Bw + (size_t)(colBase + (t >> 2)) * KK + sslot8;
  const size_t K128 = (size_t)128 * KK;
  const int ldsW = w * 512;   // wave-uniform stage dest (elems)

  // frag reads: row = (wgroup + frag*16 + lr), slot' = lg ^ ((lr>>1)&3)
  const int fslot8 = (lg ^ ((lr >> 1) & 3)) * 8;
  const int aRowOff = (wm * 128 + lr) * 32 + fslot8;
  const int bRowOff = (wn * 64 + lr) * 32 + fslot8;

  f32x4 acc[8][4];
#pragma unroll
  for (int i = 0; i < 8; i++)
#pragma unroll
    for (int j = 0; j < 4; j++) acc[i][j] = (f32x4){0.f, 0.f, 0.f, 0.f};
  bf16x8 af[4], bfr[4];

#define STGA(tt, KH, DB) { \
    const u16* g_ = Ag + (size_t)(tt) * 64 + (KH) * 32; \
    GLOAD16(g_, Sh + ((DB) * 2 + (KH)) * 8192 + ldsW); \
    GLOAD16(g_ + K128, Sh + ((DB) * 2 + (KH)) * 8192 + 4096 + ldsW); }
#define STGB(tt, KH, DB) { \
    const u16* g_ = Bg + (size_t)(tt) * 64 + (KH) * 32; \
    GLOAD16(g_, Sh + 32768 + ((DB) * 2 + (KH)) * 8192 + ldsW); \
    GLOAD16(g_ + K128, Sh + 32768 + ((DB) * 2 + (KH)) * 8192 + 4096 + ldsW); }

#define PHASE(DD, KH, MG, DOB, STG, WT) do { \
    const u16* sa_ = Sh + ((DD) * 2 + (KH)) * 8192 + aRowOff; \
    _Pragma("unroll") \
    for (int mi = 0; mi < 4; mi++) af[mi] = *(const bf16x8*)(sa_ + ((MG) * 4 + mi) * 512); \
    if (DOB) { \
      const u16* sb_ = Sh + 32768 + ((DD) * 2 + (KH)) * 8192 + bRowOff; \
      _Pragma("unroll") \
      for (int n = 0; n < 4; n++) bfr[n] = *(const bf16x8*)(sb_ + n * 512); \
    } \
    STG; \
    __builtin_amdgcn_s_barrier(); \
    asm volatile("s_waitcnt lgkmcnt(0)" ::: "memory"); \
    __builtin_amdgcn_sched_barrier(0); \
    __builtin_amdgcn_s_setprio(1); \
    _Pragma("unroll") \
    for (int mi = 0; mi < 4; mi++) { \
      _Pragma("unroll") \
      for (int n = 0; n < 4; n++) \
        acc[(MG) * 4 + mi][n] = \
            __builtin_amdgcn_mfma_f32_16x16x32_bf16(af[mi], bfr[n], acc[(MG) * 4 + mi][n], 0, 0, 0); \
    } \
    __builtin_amdgcn_s_setprio(0); \
    WT; \
    __builtin_amdgcn_s_barrier(); \
  } while (0)

#define WTC(NN) asm volatile("s_waitcnt vmcnt(" #NN ")" ::: "memory")

  // prologue: K0 (both halves) + K1.kh0 issued (12 loads); force K0.kh0 (leave 8)
  STGA(0, 0, 0); STGB(0, 0, 0);
  STGA(0, 1, 0); STGB(0, 1, 0);
  STGA(1, 0, 1); STGB(1, 0, 1);
  WTC(8);
  __builtin_amdgcn_s_barrier();

  const int NIT = KK / 128;   // 2 K-tiles per iteration
  int t0 = 0;
  for (int it = 0; it < NIT - 1; ++it, t0 += 2) {
    PHASE(0, 0, 0, 1, STGA(t0 + 1, 1, 1), );            // reads (t0).kh0
    PHASE(0, 0, 1, 0, STGB(t0 + 1, 1, 1), WTC(8));      // forces (t0).kh1
    PHASE(0, 1, 0, 1, STGA(t0 + 2, 0, 0), );            // reads (t0).kh1
    PHASE(0, 1, 1, 0, STGB(t0 + 2, 0, 0), WTC(8));      // forces (t0+1).kh0
    PHASE(1, 0, 0, 1, STGA(t0 + 2, 1, 0), );            // reads (t0+1).kh0
    PHASE(1, 0, 1, 0, STGB(t0 + 2, 1, 0), WTC(8));      // forces (t0+1).kh1
    PHASE(1, 1, 0, 1, STGA(t0 + 3, 0, 1), );            // reads (t0+1).kh1
    PHASE(1, 1, 1, 0, STGB(t0 + 3, 0, 1), WTC(8));      // forces (t0+2).kh0
  }
  // peeled last iteration (K-tiles t0, t0+1): stage only (t0+1).kh1
  PHASE(0, 0, 0, 1, STGA(t0 + 1, 1, 1), );
  PHASE(0, 0, 1, 0, STGB(t0 + 1, 1, 1), WTC(8));        // forces (t0).kh1
  PHASE(0, 1, 0, 1, , );
  PHASE(0, 1, 1, 0, , WTC(4));                          // forces (t0+1).kh0
  PHASE(1, 0, 0, 1, , );
  PHASE(1, 0, 1, 0, , WTC(0));                          // forces (t0+1).kh1
  PHASE(1, 1, 0, 1, , );
  PHASE(1, 1, 1, 0, , );
#undef PHASE
#undef STGA
#undef STGB
#undef WTC

  // epilogue: bias + bf16 store
  const int orow0 = rowBase + wm * 128 + lg * 4;
  const int ocol0 = colBase + wn * 64 + lr;
#pragma unroll
  for (int m = 0; m < 8; m++) {
#pragma unroll
    for (int n = 0; n < 4; n++) {
      const int col = ocol0 + n * 16;
      const float bv = bias[col];
#pragma unroll
      for (int r = 0; r < 4; r++) {
        const int row = orow0 + m * 16 + r;
        C[(size_t)row * N + col] = f2bf(acc[m][n][r] + bv);
      }
    }
  }
}

// ---------- small GEMM (fine-pipelined, BM=256 BN=128 BK=32, ring-3) ----------
// MODE 1: bf16 out, row -> s=row>>7,b=row&127; += posenc[s][col]; out[(b*64+s)*1024+col]
// MODE 2: f32 out, row -> s=row&63,b=row>>6; out[(s*128+b)*1024+col]
template <int MODE>
__global__ __launch_bounds__(256, 2) void gemm_fp(const u16* __restrict__ A,
                                                  const u16* __restrict__ Bw,
                                                  const float* __restrict__ bias,
                                                  void* __restrict__ Cout,
                                                  int N, int K,
                                                  const float* __restrict__ posenc) {
  __shared__ u16 SA[3][8192];
  __shared__ u16 SB[3][4096];
  const int t = threadIdx.x, w = t >> 6, l = t & 63;
  const int lr = l & 15, lg = l >> 4;
  const int wm = w >> 1, wn = w & 1;

  const int gx = gridDim.x;
  const int nb = gx * gridDim.y;
  const int id = blockIdx.y * gx + blockIdx.x;
  const int id2 = (id & 7) * (nb >> 3) + (id >> 3);
  const int rowBase = (id2 / gx) * 256, colBase = (id2 % gx) * 128;

  const int srow = l >> 2;
  const int ssl = ((l & 3) ^ (srow & 3)) * 8;
  const u16* Ag = A + (size_t)(rowBase + w * 16 + srow) * K + ssl;
  const u16* Bg = Bw + (size_t)(colBase + w * 16 + srow) * K + ssl;
  u16* const lA = &SA[0][0] + w * 512;
  u16* const lB = &SB[0][0] + w * 512;

  const int fsw = (lg ^ (lr & 3)) * 8;
  const int aoff = (wm * 128 + lr) * 32 + fsw;
  const int boff = (wn * 64 + lr) * 32 + fsw;

  f32x4 acc[8][4];
#pragma unroll
  for (int i = 0; i < 8; i++)
#pragma unroll
    for (int j = 0; j < 4; j++) acc[i][j] = (f32x4){0.f, 0.f, 0.f, 0.f};

#define STG_P0(tt, bb) do { \
    const size_t ko_ = (size_t)(tt) * 32; \
    GLOAD16(Ag + ko_,                    lA + (bb) * 8192); \
    GLOAD16(Ag + ko_ + (size_t)64 * K,   lA + (bb) * 8192 + 2048); \
    GLOAD16(Ag + ko_ + (size_t)128 * K,  lA + (bb) * 8192 + 4096); \
  } while (0)
#define STG_P1(tt, bb) do { \
    const size_t ko_ = (size_t)(tt) * 32; \
    GLOAD16(Ag + ko_ + (size_t)192 * K,  lA + (bb) * 8192 + 6144); \
    GLOAD16(Bg + ko_,                    lB + (bb) * 4096); \
    GLOAD16(Bg + ko_ + (size_t)64 * K,   lB + (bb) * 4096 + 2048); \
  } while (0)

  const int nt = K >> 5;
  STG_P0(0, 0); STG_P1(0, 0);
  STG_P0(1, 1); STG_P1(1, 1);
  asm volatile("s_waitcnt vmcnt(6)" ::: "memory");
  __builtin_amdgcn_s_barrier();

  int bcur = 0;
  for (int tt = 0; tt < nt; ++tt) {
    const u16* pa = &SA[bcur][0];
    const u16* pb = &SB[bcur][0];
    const int bnext = (bcur + 2 > 2) ? bcur - 1 : bcur + 2;
    bf16x8 af[4], bfr[4];

#pragma unroll
    for (int m = 0; m < 4; m++) af[m] = *(const bf16x8*)(pa + aoff + m * 512);
#pragma unroll
    for (int n = 0; n < 4; n++) bfr[n] = *(const bf16x8*)(pb + boff + n * 512);
    if (tt + 2 < nt) STG_P0(tt + 2, bnext);
    __builtin_amdgcn_s_barrier();
    asm volatile("s_waitcnt lgkmcnt(0)" ::: "memory");
    __builtin_amdgcn_sched_barrier(0);
    __builtin_amdgcn_s_setprio(1);
#pragma unroll
    for (int m = 0; m < 4; m++)
#pragma unroll
      for (int n = 0; n < 4; n++)
        acc[m][n] = __builtin_amdgcn_mfma_f32_16x16x32_bf16(af[m], bfr[n], acc[m][n], 0, 0, 0);
    __builtin_amdgcn_s_setprio(0);
    __builtin_amdgcn_s_barrier();

#pragma unroll
    for (int m = 0; m < 4; m++) af[m] = *(const bf16x8*)(pa + aoff + (m + 4) * 512);
    if (tt + 2 < nt) STG_P1(tt + 2, bnext);
    __builtin_amdgcn_s_barrier();
    asm volatile("s_waitcnt lgkmcnt(0)" ::: "memory");
    __builtin_amdgcn_sched_barrier(0);
    __builtin_amdgcn_s_setprio(1);
#pragma unroll
    for (int m = 0; m < 4; m++)
#pragma unroll
      for (int n = 0; n < 4; n++)
        acc[m + 4][n] = __builtin_amdgcn_mfma_f32_16x16x32_bf16(af[m], bfr[n], acc[m + 4][n], 0, 0, 0);
    __builtin_amdgcn_s_setprio(0);
    if (tt + 2 < nt) {
      asm volatile("s_waitcnt vmcnt(6)" ::: "memory");
    } else if (tt + 1 < nt) {
      asm volatile("s_waitcnt vmcnt(0)" ::: "memory");
    }
    __builtin_amdgcn_s_barrier();
    bcur = (bcur + 1 > 2) ? 0 : bcur + 1;
  }
#undef STG_P0
#undef STG_P1

  const int orow0 = rowBase + wm * 128 + lg * 4;
  const int ocol0 = colBase + wn * 64 + lr;
#pragma unroll
  for (int m = 0; m < 8; m++) {
#pragma unroll
    for (int n = 0; n < 4; n++) {
      const int col = ocol0 + n * 16;
      const float bv = bias[col];
#pragma unroll
      for (int r = 0; r < 4; r++) {
        const int row = orow0 + m * 16 + r;
        float v = acc[m][n][r] + bv;
        if (MODE == 1) {
          int s = row >> 7, b = row & 127;
          v += posenc[s * 1024 + col];
          ((u16*)Cout)[((size_t)(b * 64 + s)) * 1024 + col] = f2bf(v);
        } else {
          int s = row & 63, b = row >> 6;
          ((float*)Cout)[((size_t)(s * 128 + b)) * 1024 + col] = v;
        }
      }
    }
  }
}

// ---------- attention A ----------
__global__ __launch_bounds__(256) void attn1_kernel(const u16* __restrict__ qkv,
                                                    u16* __restrict__ am, int seqBase) {
  const int w = threadIdx.x >> 6, l = threadIdx.x & 63;
  const int pair = blockIdx.x * 4 + w;
  const int seq = pair >> 3, head = pair & 7;
  const int d0 = l * 2;
  const u16* base = qkv + (size_t)(seq * 4) * 3072 + head * 128 + d0;
  const float scale = 0.08838834764831845f;
  float q[4][2], k[4][2], v[4][2];
#pragma unroll
  for (int m = 0; m < 4; m++) {
    ushort2 uq = *(const ushort2*)(base + (size_t)m * 3072);
    ushort2 uk = *(const ushort2*)(base + (size_t)m * 3072 + 1024);
    ushort2 uv = *(const ushort2*)(base + (size_t)m * 3072 + 2048);
    q[m][0] = bf2f(uq.x) * scale; q[m][1] = bf2f(uq.y) * scale;
    k[m][0] = bf2f(uk.x);         k[m][1] = bf2f(uk.y);
    v[m][0] = bf2f(uv.x);         v[m][1] = bf2f(uv.y);
  }
  float sc[4][4];
#pragma unroll
  for (int i = 0; i < 4; i++)
#pragma unroll
    for (int j = 0; j < 4; j++)
      sc[i][j] = q[i][0] * k[j][0] + q[i][1] * k[j][1];
#pragma unroll
  for (int off = 32; off >= 1; off >>= 1)
#pragma unroll
    for (int i = 0; i < 4; i++)
#pragma unroll
      for (int j = 0; j < 4; j++)
        sc[i][j] += __shfl_xor(sc[i][j], off, 64);
  float pbar[4] = {0.f, 0.f, 0.f, 0.f};
#pragma unroll
  for (int i = 0; i < 4; i++) {
    float mx = fmaxf(fmaxf(sc[i][0], sc[i][1]), fmaxf(sc[i][2], sc[i][3]));
    float e0 = __expf(sc[i][0] - mx), e1 = __expf(sc[i][1] - mx);
    float e2 = __expf(sc[i][2] - mx), e3 = __expf(sc[i][3] - mx);
    float inv = 0.25f / (e0 + e1 + e2 + e3);
    pbar[0] += e0 * inv; pbar[1] += e1 * inv; pbar[2] += e2 * inv; pbar[3] += e3 * inv;
  }
  float o0 = pbar[0] * v[0][0] + pbar[1] * v[1][0] + pbar[2] * v[2][0] + pbar[3] * v[3][0];
  float o1 = pbar[0] * v[0][1] + pbar[1] * v[1][1] + pbar[2] * v[2][1] + pbar[3] * v[3][1];
  ushort2 ou; ou.x = f2bf(o0); ou.y = f2bf(o1);
  *(ushort2*)(am + (size_t)(seqBase + seq) * 1024 + head * 128 + d0) = ou;
}

// ---------- attention B ----------
__global__ __launch_bounds__(256) void attn2_kernel(const u16* __restrict__ qkv2,
                                                    u16* __restrict__ aout) {
  __shared__ u16 Qs[64 * 128];
  __shared__ u16 Ks[64 * 128];
  __shared__ u16 Vt[128 * 72];
  __shared__ u16 Ps[64 * 72];
  const int t = threadIdx.x, w = t >> 6, l = t & 63;
  const int lr = l & 15, lg = l >> 4;
  const int b = blockIdx.x >> 3, head = blockIdx.x & 7;
  const u16* qb = qkv2 + (size_t)(b * 64) * 3072 + head * 128;

#pragma unroll
  for (int c = 0; c < 4; c++) {
    int flat = c * 256 + t;
    int row = flat >> 4, sp = flat & 15;
    int sg = (sp ^ (row & 7)) * 8;
    GLOAD16(qb + (size_t)row * 3072 + sg, Qs + (c * 256 + w * 64) * 8);
    GLOAD16(qb + 1024 + (size_t)row * 3072 + sg, Ks + (c * 256 + w * 64) * 8);
  }
  const int dd = (t & 63) * 2, kb = t >> 6;
#pragma unroll
  for (int c = 0; c < 16; c++) {
    int k = c * 4 + kb;
    ushort2 vv = *(const ushort2*)(qb + 2048 + (size_t)k * 3072 + dd);
    Vt[(size_t)dd * 72 + k] = vv.x;
    Vt[(size_t)(dd + 1) * 72 + k] = vv.y;
  }
  __syncthreads();

  f32x4 sc[4];
#pragma unroll
  for (int cb = 0; cb < 4; cb++) sc[cb] = (f32x4){0.f, 0.f, 0.f, 0.f};
#pragma unroll
  for (int ks = 0; ks < 4; ks++) {
    bf16x8 aq = *(const bf16x8*)(Qs + (w * 16 + lr) * 128 + ((ks * 4 + lg) ^ (lr & 7)) * 8);
#pragma unroll
    for (int cb = 0; cb < 4; cb++) {
      bf16x8 bk = *(const bf16x8*)(Ks + (cb * 16 + lr) * 128 + ((ks * 4 + lg) ^ (lr & 7)) * 8);
      sc[cb] = __builtin_amdgcn_mfma_f32_16x16x32_bf16(aq, bk, sc[cb], 0, 0, 0);
    }
  }

  const float scale = 0.08838834764831845f;
#pragma unroll
  for (int r = 0; r < 4; r++) {
#pragma unroll
    for (int cb = 0; cb < 4; cb++) sc[cb][r] *= scale;
    float mx = fmaxf(fmaxf(sc[0][r], sc[1][r]), fmaxf(sc[2][r], sc[3][r]));
#pragma unroll
    for (int off = 1; off < 16; off <<= 1) mx = fmaxf(mx, __shfl_xor(mx, off, 64));
    float sum = 0.f;
#pragma unroll
    for (int cb = 0; cb < 4; cb++) {
      float e = __expf(sc[cb][r] - mx);
      sum += e;
      sc[cb][r] = e;
    }
#pragma unroll
    for (int off = 1; off < 16; off <<= 1) sum += __shfl_xor(sum, off, 64);
    float inv = 1.f / sum;
    int prow = w * 16 + lg * 4 + r;
#pragma unroll
    for (int cb = 0; cb < 4; cb++)
      Ps[(size_t)prow * 72 + cb * 16 + lr] = f2bf(sc[cb][r] * inv);
  }

  f32x4 o[8];
#pragma unroll
  for (int cb = 0; cb < 8; cb++) o[cb] = (f32x4){0.f, 0.f, 0.f, 0.f};
#pragma unroll
  for (int ks = 0; ks < 2; ks++) {
    bf16x8 ap = *(const bf16x8*)(Ps + (w * 16 + lr) * 72 + ks * 32 + lg * 8);
#pragma unroll
    for (int cb = 0; cb < 8; cb++) {
      bf16x8 bv = *(const bf16x8*)(Vt + (cb * 16 + lr) * 72 + ks * 32 + lg * 8);
      o[cb] = __builtin_amdgcn_mfma_f32_16x16x32_bf16(ap, bv, o[cb], 0, 0, 0);
    }
  }
#pragma unroll
  for (int cb = 0; cb < 8; cb++) {
#pragma unroll
    for (int r = 0; r < 4; r++) {
      int srow = w * 16 + lg * 4 + r;
      int d = cb * 16 + lr;
      aout[(size_t)(b * 64 + srow) * 1024 + head * 128 + d] = f2bf(o[cb][r]);
    }
  }
}

extern "C" void kernel_launch(void* const* d_in, const int* in_sizes, int n_in,
                              void* d_out, int out_size, void* d_ws, size_t ws_size,
                              hipStream_t stream) {
  const float* hidden   = (const float*)d_in[0];
  const float* mf_in_w  = (const float*)d_in[1];
  const float* mf_in_b  = (const float*)d_in[2];
  const float* mf_out_w = (const float*)d_in[3];
  const float* mf_out_b = (const float*)d_in[4];
  const float* sf_in_w  = (const float*)d_in[5];
  const float* sf_in_b  = (const float*)d_in[6];
  const float* sf_out_w = (const float*)d_in[7];
  const float* sf_out_b = (const float*)d_in[8];
  const float* pos_enc  = (const float*)d_in[9];

  char* ws = (char*)d_ws;
  u16* w_mf_in  = (u16*)(ws);              // 6291456
  u16* w_mf_out = (u16*)(ws + 6291456);    // 2097152
  u16* w_sf_in  = (u16*)(ws + 8388608);    // 6291456
  u16* w_sf_out = (u16*)(ws + 14680064);   // 2097152

  cvtw_kernel<<<3072, 256, 0, stream>>>(mf_in_w, w_mf_in, 786432);
  cvtw_kernel<<<1024, 256, 0, stream>>>(mf_out_w, w_mf_out, 262144);
  cvtw_kernel<<<3072, 256, 0, stream>>>(sf_in_w, w_sf_in, 786432);
  cvtw_kernel<<<1024, 256, 0, stream>>>(sf_out_w, w_sf_out, 262144);

  if (ws_size >= 335544320ull) {
    // full-M path: one GEMM1 dispatch over all 32768 rows
    u16* xfull    = (u16*)(ws + 16777216);   // 64 MB
    u16* qkvfull  = (u16*)(ws + 83886080);   // 192 MB
    u16* attnmean = (u16*)(ws + 285212672);  // 16 MB
    u16* seqbuf   = (u16*)(ws + 301989888);  // 16 MB
    u16* a2out    = (u16*)(ws + 318767104);  // 16 MB -> 320 MB total

    xcvt_kernel<<<32768, 256, 0, stream>>>(hidden, xfull, 0);
    gemm8p<1024><<<dim3(12, 128), 512, 0, stream>>>(xfull, w_mf_in, mf_in_b, qkvfull, 3072);
    attn1_kernel<<<16384, 256, 0, stream>>>(qkvfull, attnmean, 0);

    gemm_fp<1><<<dim3(8, 32), 256, 0, stream>>>(attnmean, w_mf_out, mf_out_b, seqbuf,
                                                1024, 1024, pos_enc);
    gemm8p<1024><<<dim3(12, 32), 512, 0, stream>>>(seqbuf, w_sf_in, sf_in_b, qkvfull, 3072);
    attn2_kernel<<<1024, 256, 0, stream>>>(qkvfull, a2out);
    gemm_fp<2><<<dim3(8, 32), 256, 0, stream>>>(a2out, w_sf_out, sf_out_b, d_out,
                                                1024, 1024, nullptr);
  } else {
    // chunked fallback (128 MB)
    u16* xchunk   = (u16*)(ws + 16777216);
    u16* qkvbuf   = (u16*)(ws + 33554432);
    u16* attnmean = (u16*)(ws + 83886080);
    u16* seqbuf   = (u16*)(ws + 100663296);
    u16* a2out    = (u16*)(ws + 117440512);

    for (int c = 0; c < 4; ++c) {
      xcvt_kernel<<<8192, 256, 0, stream>>>(hidden, xchunk, c * 16);
      gemm8p<1024><<<dim3(12, 32), 512, 0, stream>>>(xchunk, w_mf_in, mf_in_b, qkvbuf, 3072);
      attn1_kernel<<<4096, 256, 0, stream>>>(qkvbuf, attnmean, c * 2048);
    }

    gemm_fp<1><<<dim3(8, 32), 256, 0, stream>>>(attnmean, w_mf_out, mf_out_b, seqbuf,
                                                1024, 1024, pos_enc);
    gemm8p<1024><<<dim3(12, 32), 512, 0, stream>>>(seqbuf, w_sf_in, sf_in_b, qkvbuf, 3072);
    attn2_kernel<<<1024, 256, 0, stream>>>(qkvbuf, a2out);
    gemm_fp<2><<<dim3(8, 32), 256, 0, stream>>>(a2out, w_sf_out, sf_out_b, d_out,
                                                1024, 1024, nullptr);
  }
}

// Round 7
// 471.495 us; speedup vs baseline: 1.3587x; 1.0083x over previous
//
#include <hip/hip_runtime.h>

typedef unsigned short u16;
typedef __attribute__((ext_vector_type(8))) short bf16x8;
typedef __attribute__((ext_vector_type(4))) float f32x4;

__device__ __forceinline__ u16 f2bf(float f) {
  unsigned u = __float_as_uint(f);
  u += 0x7FFFu + ((u >> 16) & 1u);
  return (u16)(u >> 16);
}
__device__ __forceinline__ float bf2f(u16 h) {
  return __uint_as_float(((unsigned)h) << 16);
}

#define GLOAD16(g, l) __builtin_amdgcn_global_load_lds( \
    (const __attribute__((address_space(1))) void*)(g), \
    (__attribute__((address_space(3))) void*)(l), 16, 0, 0)

// ---------- elementwise converts ----------
__global__ __launch_bounds__(256) void cvtw_kernel(const float* __restrict__ in,
                                                   u16* __restrict__ out, int n4) {
  int i = blockIdx.x * 256 + threadIdx.x;
  if (i >= n4) return;
  float4 f = ((const float4*)in)[i];
  ushort4 u;
  u.x = f2bf(f.x); u.y = f2bf(f.y); u.z = f2bf(f.z); u.w = f2bf(f.w);
  ((ushort4*)out)[i] = u;
}

// gather x rows = ((s-s0)*128 + b)*4 + m from hidden[s][m][b][0][h]
__global__ __launch_bounds__(256) void xcvt_kernel(const float* __restrict__ hidden,
                                                   u16* __restrict__ xb, int s0) {
  int idx = blockIdx.x * 256 + threadIdx.x;
  int h4 = idx & 255;
  int lrow = idx >> 8;
  int m = lrow & 3;
  int b = (lrow >> 2) & 127;
  int sl = lrow >> 9;
  int s = s0 + sl;
  const float4 f = *(const float4*)(hidden + (((size_t)(s * 4 + m) * 128 + b) * 1024) + h4 * 4);
  ushort4 u;
  u.x = f2bf(f.x); u.y = f2bf(f.y); u.z = f2bf(f.z); u.w = f2bf(f.w);
  *(ushort4*)(xb + (size_t)lrow * 1024 + h4 * 4) = u;
}

// ---------- 8-phase 256x256 GEMM, BK=64, 8 waves ----------
// Pipelined ds_reads (one phase ahead, counted lgkmcnt, double-buffered frags),
// single barrier per phase, vmcnt(6) at even-phase ends.
// C[m,n] = sum_k A[m,k]*Bw[n,k] + bias[n], bf16 out. KK = K (compile-time).
// LDS slabs: A(d,kh) at ((d*2+kh)*8192), B at +32768; slab = 256 rows x 32 k,
// row stride 32 elems, 4x16B slots/row, slot' = slot ^ ((row>>1)&3).
template <int KK>
__global__ __launch_bounds__(512, 2) void gemm8p(const u16* __restrict__ A,
                                                 const u16* __restrict__ Bw,
                                                 const float* __restrict__ bias,
                                                 u16* __restrict__ C, int N) {
  __shared__ u16 Sh[65536];   // 128 KB
  const int t = threadIdx.x, w = t >> 6, l = t & 63;
  const int lr = l & 15, lg = l >> 4;
  const int wm = w >> 2, wn = w & 3;

  // XCD-aware bijective swizzle (grid blocks % 8 == 0)
  const int gx = gridDim.x;
  const int nb = gx * gridDim.y;
  const int id = blockIdx.y * gx + blockIdx.x;
  const int id2 = (id & 7) * (nb >> 3) + (id >> 3);
  const int rowBase = (id2 / gx) * 256, colBase = (id2 % gx) * 256;

  // staging: lane t -> slab row (t>>2), slot' (t&3); source slot = (t&3)^((t>>3)&3)
  const int sslot8 = ((t & 3) ^ ((t >> 3) & 3)) * 8;
  const u16* Ag = A + (size_t)(rowBase + (t >> 2)) * KK + sslot8;
  const u16* Bg = Bw + (size_t)(colBase + (t >> 2)) * KK + sslot8;
  const size_t K128 = (size_t)128 * KK;
  const int ldsW = w * 512;   // wave-uniform stage dest (elems)

  // frag reads: row*(32) + (lg ^ ((row>>1)&3))*8 ; row&3 == lr&3
  const int fslot8 = (lg ^ ((lr >> 1) & 3)) * 8;
  const int aRowOff = (wm * 128 + lr) * 32 + fslot8;
  const int bRowOff = (wn * 64 + lr) * 32 + fslot8;

  f32x4 acc[8][4];
#pragma unroll
  for (int i = 0; i < 8; i++)
#pragma unroll
    for (int j = 0; j < 4; j++) acc[i][j] = (f32x4){0.f, 0.f, 0.f, 0.f};
  bf16x8 af[2][4], bfr[2][4];   // double-buffered fragment regs (static indices)

#define STGA(tt, KH, DB) { \
    const u16* g_ = Ag + (size_t)(tt) * 64 + (KH) * 32; \
    GLOAD16(g_, Sh + ((DB) * 2 + (KH)) * 8192 + ldsW); \
    GLOAD16(g_ + K128, Sh + ((DB) * 2 + (KH)) * 8192 + 4096 + ldsW); }
#define STGB(tt, KH, DB) { \
    const u16* g_ = Bg + (size_t)(tt) * 64 + (KH) * 32; \
    GLOAD16(g_, Sh + 32768 + ((DB) * 2 + (KH)) * 8192 + ldsW); \
    GLOAD16(g_ + K128, Sh + 32768 + ((DB) * 2 + (KH)) * 8192 + 4096 + ldsW); }

#define RA(DD, KH, MG, BUF) { \
    const u16* sa_ = Sh + ((DD) * 2 + (KH)) * 8192 + aRowOff; \
    _Pragma("unroll") \
    for (int mi = 0; mi < 4; mi++) af[BUF][mi] = *(const bf16x8*)(sa_ + ((MG) * 4 + mi) * 512); }
#define RB(DD, KH, BUF) { \
    const u16* sb_ = Sh + 32768 + ((DD) * 2 + (KH)) * 8192 + bRowOff; \
    _Pragma("unroll") \
    for (int n = 0; n < 4; n++) bfr[BUF][n] = *(const bf16x8*)(sb_ + n * 512); }

#define LG(NN) asm volatile("s_waitcnt lgkmcnt(" #NN ")" ::: "memory"); \
               __builtin_amdgcn_sched_barrier(0)
#define WTC(NN) asm volatile("s_waitcnt vmcnt(" #NN ")" ::: "memory")
#define BAR __builtin_amdgcn_s_barrier()

#define MM(MG, AB, BB) { \
    __builtin_amdgcn_s_setprio(1); \
    _Pragma("unroll") \
    for (int mi = 0; mi < 4; mi++) { \
      _Pragma("unroll") \
      for (int n = 0; n < 4; n++) \
        acc[(MG) * 4 + mi][n] = __builtin_amdgcn_mfma_f32_16x16x32_bf16( \
            af[AB][mi], bfr[BB][n], acc[(MG) * 4 + mi][n], 0, 0, 0); \
    } \
    __builtin_amdgcn_s_setprio(0); }

  // prologue: stage K0 (both halves) + K1.kh0 (12 loads); force K0.kh0 (leave 8)
  STGA(0, 0, 0); STGB(0, 0, 0);
  STGA(0, 1, 0); STGB(0, 1, 0);
  STGA(1, 0, 1); STGB(1, 0, 1);
  WTC(8);
  BAR;
  RA(0, 0, 0, 0); RB(0, 0, 0);   // frags for ph0 (8 reads outstanding)

  const int NIT = KK / 128;   // 2 K-tiles per iteration
  int t0 = 0;
  for (int it = 0; it < NIT - 1; ++it, t0 += 2) {
    // ph0
    STGA(t0 + 1, 1, 1); RA(0, 0, 1, 1);              LG(4); MM(0, 0, 0); WTC(6); BAR;
    // ph1
    STGB(t0 + 1, 1, 1); RA(0, 1, 0, 0); RB(0, 1, 1); LG(8); MM(1, 1, 0);         BAR;
    // ph2
    STGA(t0 + 2, 0, 0); RA(0, 1, 1, 1);              LG(4); MM(0, 0, 1); WTC(6); BAR;
    // ph3
    STGB(t0 + 2, 0, 0); RA(1, 0, 0, 0); RB(1, 0, 0); LG(8); MM(1, 1, 1);         BAR;
    // ph4
    STGA(t0 + 2, 1, 0); RA(1, 0, 1, 1);              LG(4); MM(0, 0, 0); WTC(6); BAR;
    // ph5
    STGB(t0 + 2, 1, 0); RA(1, 1, 0, 0); RB(1, 1, 1); LG(8); MM(1, 1, 0);         BAR;
    // ph6
    STGA(t0 + 3, 0, 1); RA(1, 1, 1, 1);              LG(4); MM(0, 0, 1); WTC(6); BAR;
    // ph7
    STGB(t0 + 3, 0, 1); RA(0, 0, 0, 0); RB(0, 0, 0); LG(8); MM(1, 1, 1);         BAR;
  }
  // peeled last iteration: stage only (t0+1).kh1; drain vmcnt 6/4/0
  STGA(t0 + 1, 1, 1); RA(0, 0, 1, 1);              LG(4); MM(0, 0, 0); WTC(6); BAR;
  STGB(t0 + 1, 1, 1); RA(0, 1, 0, 0); RB(0, 1, 1); LG(8); MM(1, 1, 0);         BAR;
  RA(0, 1, 1, 1);                                  LG(4); MM(0, 0, 1); WTC(4); BAR;
  RA(1, 0, 0, 0); RB(1, 0, 0);                     LG(8); MM(1, 1, 1);         BAR;
  RA(1, 0, 1, 1);                                  LG(4); MM(0, 0, 0); WTC(0); BAR;
  RA(1, 1, 0, 0); RB(1, 1, 1);                     LG(8); MM(1, 1, 0);         BAR;
  RA(1, 1, 1, 1);                                  LG(4); MM(0, 0, 1);         BAR;
                                                   LG(0); MM(1, 1, 1);
#undef MM
#undef BAR
#undef WTC
#undef LG
#undef RB
#undef RA
#undef STGB
#undef STGA

  // epilogue: bias + bf16 store
  const int orow0 = rowBase + wm * 128 + lg * 4;
  const int ocol0 = colBase + wn * 64 + lr;
#pragma unroll
  for (int m = 0; m < 8; m++) {
#pragma unroll
    for (int n = 0; n < 4; n++) {
      const int col = ocol0 + n * 16;
      const float bv = bias[col];
#pragma unroll
      for (int r = 0; r < 4; r++) {
        const int row = orow0 + m * 16 + r;
        C[(size_t)row * N + col] = f2bf(acc[m][n][r] + bv);
      }
    }
  }
}

// ---------- small GEMM (fine-pipelined, BM=256 BN=128 BK=32, ring-3) ----------
// MODE 1: bf16 out, row -> s=row>>7,b=row&127; += posenc[s][col]; out[(b*64+s)*1024+col]
// MODE 2: f32 out, row -> s=row&63,b=row>>6; out[(s*128+b)*1024+col]
template <int MODE>
__global__ __launch_bounds__(256, 2) void gemm_fp(const u16* __restrict__ A,
                                                  const u16* __restrict__ Bw,
                                                  const float* __restrict__ bias,
                                                  void* __restrict__ Cout,
                                                  int N, int K,
                                                  const float* __restrict__ posenc) {
  __shared__ u16 SA[3][8192];
  __shared__ u16 SB[3][4096];
  const int t = threadIdx.x, w = t >> 6, l = t & 63;
  const int lr = l & 15, lg = l >> 4;
  const int wm = w >> 1, wn = w & 1;

  const int gx = gridDim.x;
  const int nb = gx * gridDim.y;
  const int id = blockIdx.y * gx + blockIdx.x;
  const int id2 = (id & 7) * (nb >> 3) + (id >> 3);
  const int rowBase = (id2 / gx) * 256, colBase = (id2 % gx) * 128;

  const int srow = l >> 2;
  const int ssl = ((l & 3) ^ (srow & 3)) * 8;
  const u16* Ag = A + (size_t)(rowBase + w * 16 + srow) * K + ssl;
  const u16* Bg = Bw + (size_t)(colBase + w * 16 + srow) * K + ssl;
  u16* const lA = &SA[0][0] + w * 512;
  u16* const lB = &SB[0][0] + w * 512;

  const int fsw = (lg ^ (lr & 3)) * 8;
  const int aoff = (wm * 128 + lr) * 32 + fsw;
  const int boff = (wn * 64 + lr) * 32 + fsw;

  f32x4 acc[8][4];
#pragma unroll
  for (int i = 0; i < 8; i++)
#pragma unroll
    for (int j = 0; j < 4; j++) acc[i][j] = (f32x4){0.f, 0.f, 0.f, 0.f};

#define STG_P0(tt, bb) do { \
    const size_t ko_ = (size_t)(tt) * 32; \
    GLOAD16(Ag + ko_,                    lA + (bb) * 8192); \
    GLOAD16(Ag + ko_ + (size_t)64 * K,   lA + (bb) * 8192 + 2048); \
    GLOAD16(Ag + ko_ + (size_t)128 * K,  lA + (bb) * 8192 + 4096); \
  } while (0)
#define STG_P1(tt, bb) do { \
    const size_t ko_ = (size_t)(tt) * 32; \
    GLOAD16(Ag + ko_ + (size_t)192 * K,  lA + (bb) * 8192 + 6144); \
    GLOAD16(Bg + ko_,                    lB + (bb) * 4096); \
    GLOAD16(Bg + ko_ + (size_t)64 * K,   lB + (bb) * 4096 + 2048); \
  } while (0)

  const int nt = K >> 5;
  STG_P0(0, 0); STG_P1(0, 0);
  STG_P0(1, 1); STG_P1(1, 1);
  asm volatile("s_waitcnt vmcnt(6)" ::: "memory");
  __builtin_amdgcn_s_barrier();

  int bcur = 0;
  for (int tt = 0; tt < nt; ++tt) {
    const u16* pa = &SA[bcur][0];
    const u16* pb = &SB[bcur][0];
    const int bnext = (bcur + 2 > 2) ? bcur - 1 : bcur + 2;
    bf16x8 af[4], bfr[4];

#pragma unroll
    for (int m = 0; m < 4; m++) af[m] = *(const bf16x8*)(pa + aoff + m * 512);
#pragma unroll
    for (int n = 0; n < 4; n++) bfr[n] = *(const bf16x8*)(pb + boff + n * 512);
    if (tt + 2 < nt) STG_P0(tt + 2, bnext);
    __builtin_amdgcn_s_barrier();
    asm volatile("s_waitcnt lgkmcnt(0)" ::: "memory");
    __builtin_amdgcn_sched_barrier(0);
    __builtin_amdgcn_s_setprio(1);
#pragma unroll
    for (int m = 0; m < 4; m++)
#pragma unroll
      for (int n = 0; n < 4; n++)
        acc[m][n] = __builtin_amdgcn_mfma_f32_16x16x32_bf16(af[m], bfr[n], acc[m][n], 0, 0, 0);
    __builtin_amdgcn_s_setprio(0);
    __builtin_amdgcn_s_barrier();

#pragma unroll
    for (int m = 0; m < 4; m++) af[m] = *(const bf16x8*)(pa + aoff + (m + 4) * 512);
    if (tt + 2 < nt) STG_P1(tt + 2, bnext);
    __builtin_amdgcn_s_barrier();
    asm volatile("s_waitcnt lgkmcnt(0)" ::: "memory");
    __builtin_amdgcn_sched_barrier(0);
    __builtin_amdgcn_s_setprio(1);
#pragma unroll
    for (int m = 0; m < 4; m++)
#pragma unroll
      for (int n = 0; n < 4; n++)
        acc[m + 4][n] = __builtin_amdgcn_mfma_f32_16x16x32_bf16(af[m], bfr[n], acc[m + 4][n], 0, 0, 0);
    __builtin_amdgcn_s_setprio(0);
    if (tt + 2 < nt) {
      asm volatile("s_waitcnt vmcnt(6)" ::: "memory");
    } else if (tt + 1 < nt) {
      asm volatile("s_waitcnt vmcnt(0)" ::: "memory");
    }
    __builtin_amdgcn_s_barrier();
    bcur = (bcur + 1 > 2) ? 0 : bcur + 1;
  }
#undef STG_P0
#undef STG_P1

  const int orow0 = rowBase + wm * 128 + lg * 4;
  const int ocol0 = colBase + wn * 64 + lr;
#pragma unroll
  for (int m = 0; m < 8; m++) {
#pragma unroll
    for (int n = 0; n < 4; n++) {
      const int col = ocol0 + n * 16;
      const float bv = bias[col];
#pragma unroll
      for (int r = 0; r < 4; r++) {
        const int row = orow0 + m * 16 + r;
        float v = acc[m][n][r] + bv;
        if (MODE == 1) {
          int s = row >> 7, b = row & 127;
          v += posenc[s * 1024 + col];
          ((u16*)Cout)[((size_t)(b * 64 + s)) * 1024 + col] = f2bf(v);
        } else {
          int s = row & 63, b = row >> 6;
          ((float*)Cout)[((size_t)(s * 128 + b)) * 1024 + col] = v;
        }
      }
    }
  }
}

// ---------- attention A ----------
__global__ __launch_bounds__(256) void attn1_kernel(const u16* __restrict__ qkv,
                                                    u16* __restrict__ am, int seqBase) {
  const int w = threadIdx.x >> 6, l = threadIdx.x & 63;
  const int pair = blockIdx.x * 4 + w;
  const int seq = pair >> 3, head = pair & 7;
  const int d0 = l * 2;
  const u16* base = qkv + (size_t)(seq * 4) * 3072 + head * 128 + d0;
  const float scale = 0.08838834764831845f;
  float q[4][2], k[4][2], v[4][2];
#pragma unroll
  for (int m = 0; m < 4; m++) {
    ushort2 uq = *(const ushort2*)(base + (size_t)m * 3072);
    ushort2 uk = *(const ushort2*)(base + (size_t)m * 3072 + 1024);
    ushort2 uv = *(const ushort2*)(base + (size_t)m * 3072 + 2048);
    q[m][0] = bf2f(uq.x) * scale; q[m][1] = bf2f(uq.y) * scale;
    k[m][0] = bf2f(uk.x);         k[m][1] = bf2f(uk.y);
    v[m][0] = bf2f(uv.x);         v[m][1] = bf2f(uv.y);
  }
  float sc[4][4];
#pragma unroll
  for (int i = 0; i < 4; i++)
#pragma unroll
    for (int j = 0; j < 4; j++)
      sc[i][j] = q[i][0] * k[j][0] + q[i][1] * k[j][1];
#pragma unroll
  for (int off = 32; off >= 1; off >>= 1)
#pragma unroll
    for (int i = 0; i < 4; i++)
#pragma unroll
      for (int j = 0; j < 4; j++)
        sc[i][j] += __shfl_xor(sc[i][j], off, 64);
  float pbar[4] = {0.f, 0.f, 0.f, 0.f};
#pragma unroll
  for (int i = 0; i < 4; i++) {
    float mx = fmaxf(fmaxf(sc[i][0], sc[i][1]), fmaxf(sc[i][2], sc[i][3]));
    float e0 = __expf(sc[i][0] - mx), e1 = __expf(sc[i][1] - mx);
    float e2 = __expf(sc[i][2] - mx), e3 = __expf(sc[i][3] - mx);
    float inv = 0.25f / (e0 + e1 + e2 + e3);
    pbar[0] += e0 * inv; pbar[1] += e1 * inv; pbar[2] += e2 * inv; pbar[3] += e3 * inv;
  }
  float o0 = pbar[0] * v[0][0] + pbar[1] * v[1][0] + pbar[2] * v[2][0] + pbar[3] * v[3][0];
  float o1 = pbar[0] * v[0][1] + pbar[1] * v[1][1] + pbar[2] * v[2][1] + pbar[3] * v[3][1];
  ushort2 ou; ou.x = f2bf(o0); ou.y = f2bf(o1);
  *(ushort2*)(am + (size_t)(seqBase + seq) * 1024 + head * 128 + d0) = ou;
}

// ---------- attention B ----------
__global__ __launch_bounds__(256) void attn2_kernel(const u16* __restrict__ qkv2,
                                                    u16* __restrict__ aout) {
  __shared__ u16 Qs[64 * 128];
  __shared__ u16 Ks[64 * 128];
  __shared__ u16 Vt[128 * 72];
  __shared__ u16 Ps[64 * 72];
  const int t = threadIdx.x, w = t >> 6, l = t & 63;
  const int lr = l & 15, lg = l >> 4;
  const int b = blockIdx.x >> 3, head = blockIdx.x & 7;
  const u16* qb = qkv2 + (size_t)(b * 64) * 3072 + head * 128;

#pragma unroll
  for (int c = 0; c < 4; c++) {
    int flat = c * 256 + t;
    int row = flat >> 4, sp = flat & 15;
    int sg = (sp ^ (row & 7)) * 8;
    GLOAD16(qb + (size_t)row * 3072 + sg, Qs + (c * 256 + w * 64) * 8);
    GLOAD16(qb + 1024 + (size_t)row * 3072 + sg, Ks + (c * 256 + w * 64) * 8);
  }
  const int dd = (t & 63) * 2, kb = t >> 6;
#pragma unroll
  for (int c = 0; c < 16; c++) {
    int k = c * 4 + kb;
    ushort2 vv = *(const ushort2*)(qb + 2048 + (size_t)k * 3072 + dd);
    Vt[(size_t)dd * 72 + k] = vv.x;
    Vt[(size_t)(dd + 1) * 72 + k] = vv.y;
  }
  __syncthreads();

  f32x4 sc[4];
#pragma unroll
  for (int cb = 0; cb < 4; cb++) sc[cb] = (f32x4){0.f, 0.f, 0.f, 0.f};
#pragma unroll
  for (int ks = 0; ks < 4; ks++) {
    bf16x8 aq = *(const bf16x8*)(Qs + (w * 16 + lr) * 128 + ((ks * 4 + lg) ^ (lr & 7)) * 8);
#pragma unroll
    for (int cb = 0; cb < 4; cb++) {
      bf16x8 bk = *(const bf16x8*)(Ks + (cb * 16 + lr) * 128 + ((ks * 4 + lg) ^ (lr & 7)) * 8);
      sc[cb] = __builtin_amdgcn_mfma_f32_16x16x32_bf16(aq, bk, sc[cb], 0, 0, 0);
    }
  }

  const float scale = 0.08838834764831845f;
#pragma unroll
  for (int r = 0; r < 4; r++) {
#pragma unroll
    for (int cb = 0; cb < 4; cb++) sc[cb][r] *= scale;
    float mx = fmaxf(fmaxf(sc[0][r], sc[1][r]), fmaxf(sc[2][r], sc[3][r]));
#pragma unroll
    for (int off = 1; off < 16; off <<= 1) mx = fmaxf(mx, __shfl_xor(mx, off, 64));
    float sum = 0.f;
#pragma unroll
    for (int cb = 0; cb < 4; cb++) {
      float e = __expf(sc[cb][r] - mx);
      sum += e;
      sc[cb][r] = e;
    }
#pragma unroll
    for (int off = 1; off < 16; off <<= 1) sum += __shfl_xor(sum, off, 64);
    float inv = 1.f / sum;
    int prow = w * 16 + lg * 4 + r;
#pragma unroll
    for (int cb = 0; cb < 4; cb++)
      Ps[(size_t)prow * 72 + cb * 16 + lr] = f2bf(sc[cb][r] * inv);
  }

  f32x4 o[8];
#pragma unroll
  for (int cb = 0; cb < 8; cb++) o[cb] = (f32x4){0.f, 0.f, 0.f, 0.f};
#pragma unroll
  for (int ks = 0; ks < 2; ks++) {
    bf16x8 ap = *(const bf16x8*)(Ps + (w * 16 + lr) * 72 + ks * 32 + lg * 8);
#pragma unroll
    for (int cb = 0; cb < 8; cb++) {
      bf16x8 bv = *(const bf16x8*)(Vt + (cb * 16 + lr) * 72 + ks * 32 + lg * 8);
      o[cb] = __builtin_amdgcn_mfma_f32_16x16x32_bf16(ap, bv, o[cb], 0, 0, 0);
    }
  }
#pragma unroll
  for (int cb = 0; cb < 8; cb++) {
#pragma unroll
    for (int r = 0; r < 4; r++) {
      int srow = w * 16 + lg * 4 + r;
      int d = cb * 16 + lr;
      aout[(size_t)(b * 64 + srow) * 1024 + head * 128 + d] = f2bf(o[cb][r]);
    }
  }
}

extern "C" void kernel_launch(void* const* d_in, const int* in_sizes, int n_in,
                              void* d_out, int out_size, void* d_ws, size_t ws_size,
                              hipStream_t stream) {
  const float* hidden   = (const float*)d_in[0];
  const float* mf_in_w  = (const float*)d_in[1];
  const float* mf_in_b  = (const float*)d_in[2];
  const float* mf_out_w = (const float*)d_in[3];
  const float* mf_out_b = (const float*)d_in[4];
  const float* sf_in_w  = (const float*)d_in[5];
  const float* sf_in_b  = (const float*)d_in[6];
  const float* sf_out_w = (const float*)d_in[7];
  const float* sf_out_b = (const float*)d_in[8];
  const float* pos_enc  = (const float*)d_in[9];

  char* ws = (char*)d_ws;
  u16* w_mf_in  = (u16*)(ws);              // 6291456
  u16* w_mf_out = (u16*)(ws + 6291456);    // 2097152
  u16* w_sf_in  = (u16*)(ws + 8388608);    // 6291456
  u16* w_sf_out = (u16*)(ws + 14680064);   // 2097152

  cvtw_kernel<<<3072, 256, 0, stream>>>(mf_in_w, w_mf_in, 786432);
  cvtw_kernel<<<1024, 256, 0, stream>>>(mf_out_w, w_mf_out, 262144);
  cvtw_kernel<<<3072, 256, 0, stream>>>(sf_in_w, w_sf_in, 786432);
  cvtw_kernel<<<1024, 256, 0, stream>>>(sf_out_w, w_sf_out, 262144);

  if (ws_size >= 335544320ull) {
    // full-M path: one GEMM1 dispatch over all 32768 rows
    u16* xfull    = (u16*)(ws + 16777216);   // 64 MB
    u16* qkvfull  = (u16*)(ws + 83886080);   // 192 MB
    u16* attnmean = (u16*)(ws + 285212672);  // 16 MB
    u16* seqbuf   = (u16*)(ws + 301989888);  // 16 MB
    u16* a2out    = (u16*)(ws + 318767104);  // 16 MB -> 320 MB total

    xcvt_kernel<<<32768, 256, 0, stream>>>(hidden, xfull, 0);
    gemm8p<1024><<<dim3(12, 128), 512, 0, stream>>>(xfull, w_mf_in, mf_in_b, qkvfull, 3072);
    attn1_kernel<<<16384, 256, 0, stream>>>(qkvfull, attnmean, 0);

    gemm_fp<1><<<dim3(8, 32), 256, 0, stream>>>(attnmean, w_mf_out, mf_out_b, seqbuf,
                                                1024, 1024, pos_enc);
    gemm8p<1024><<<dim3(12, 32), 512, 0, stream>>>(seqbuf, w_sf_in, sf_in_b, qkvfull, 3072);
    attn2_kernel<<<1024, 256, 0, stream>>>(qkvfull, a2out);
    gemm_fp<2><<<dim3(8, 32), 256, 0, stream>>>(a2out, w_sf_out, sf_out_b, d_out,
                                                1024, 1024, nullptr);
  } else {
    // chunked fallback (128 MB)
    u16* xchunk   = (u16*)(ws + 16777216);
    u16* qkvbuf   = (u16*)(ws + 33554432);
    u16* attnmean = (u16*)(ws + 83886080);
    u16* seqbuf   = (u16*)(ws + 100663296);
    u16* a2out    = (u16*)(ws + 117440512);

    for (int c = 0; c < 4; ++c) {
      xcvt_kernel<<<8192, 256, 0, stream>>>(hidden, xchunk, c * 16);
      gemm8p<1024><<<dim3(12, 32), 512, 0, stream>>>(xchunk, w_mf_in, mf_in_b, qkvbuf, 3072);
      attn1_kernel<<<4096, 256, 0, stream>>>(qkvbuf, attnmean, c * 2048);
    }

    gemm_fp<1><<<dim3(8, 32), 256, 0, stream>>>(attnmean, w_mf_out, mf_out_b, seqbuf,
                                                1024, 1024, pos_enc);
    gemm8p<1024><<<dim3(12, 32), 512, 0, stream>>>(seqbuf, w_sf_in, sf_in_b, qkvbuf, 3072);
    attn2_kernel<<<1024, 256, 0, stream>>>(qkvbuf, a2out);
    gemm_fp<2><<<dim3(8, 32), 256, 0, stream>>>(a2out, w_sf_out, sf_out_b, d_out,
                                                1024, 1024, nullptr);
  }
}